// Round 1
// baseline (4510.301 us; speedup 1.0000x reference)
//
#include <hip/hip_runtime.h>
#include <cstdio>
#include <math.h>

#define NB 16
#define NC 512
#define T0 64
#define NOSC 128
#define UPLEN 24576
#define NTOT 16384
#define NWIN 32
#define NFRAMES 1024
#define NCROP 4096
#define NCHUNK 96
#define CHT 256

#define TWO_PI_D 6.283185307179586
#define INV_2PI_D 0.15915494309189535
#define K_PHASE (6.283185307179586/11025.0)

static __device__ __forceinline__ float lrelu_f(float x){ return x > 0.f ? x : 0.2f*x; }

// ---------------- tables: centers (np.geomspace(20, 5492.5, 128)) + erbs ----------------
__global__ void k_tables(float* __restrict__ centers, float* __restrict__ erbs){
  int o = threadIdx.x;
  if (o < NOSC){
    double lg0 = log10(20.0);
    double lg1 = log10(5492.5);
    double e = (o == NOSC-1) ? lg1 : (o*(lg1-lg0))/(double)(NOSC-1) + lg0;
    float c = (float)pow(10.0, e);
    centers[o] = c;
    erbs[o] = c*0.108f + 24.7f;
  }
}

// ---------------- pointwise conv + lrelu (f64 accumulate) ----------------
// in [NB,Cin,64], w [Cout,Cin], out [NB,Cout,64]
__global__ __launch_bounds__(256) void k_conv1(const float* __restrict__ in, const float* __restrict__ w,
                                               float* __restrict__ out, int Cin, int Cout){
  int b = blockIdx.x;
  int lane = threadIdx.x & 63, wv = threadIdx.x >> 6;
  int co0 = blockIdx.y*16 + wv*4;
  const float* inb = in + (size_t)b*Cin*T0 + lane;
  double a[4] = {0.0,0.0,0.0,0.0};
  for (int ci = 0; ci < Cin; ++ci){
    double v = (double)inb[(size_t)ci*T0];
    #pragma unroll
    for (int j = 0; j < 4; ++j) a[j] += v * (double)w[(size_t)(co0+j)*Cin + ci];
  }
  #pragma unroll
  for (int j = 0; j < 4; ++j)
    out[((size_t)b*Cout + co0 + j)*T0 + lane] = lrelu_f((float)a[j]);
}

// ---------------- k=3 conv + lrelu (pad 1, f64 accumulate) ----------------
__global__ __launch_bounds__(256) void k_conv3(const float* __restrict__ in, const float* __restrict__ w,
                                               float* __restrict__ out){
  int b = blockIdx.x;
  int lane = threadIdx.x & 63, wv = threadIdx.x >> 6;
  int co0 = blockIdx.y*16 + wv*4;
  const float* inb = in + (size_t)b*NC*T0;
  double a[4] = {0.0,0.0,0.0,0.0};
  for (int ci = 0; ci < NC; ++ci){
    const float* row = inb + (size_t)ci*T0;
    float rm = (lane > 0)  ? row[lane-1] : 0.f;
    float r0 = row[lane];
    float rp = (lane < 63) ? row[lane+1] : 0.f;
    #pragma unroll
    for (int j = 0; j < 4; ++j){
      const float* wp = w + ((size_t)(co0+j)*NC + ci)*3;
      a[j] += (double)wp[0]*(double)rm + (double)wp[1]*(double)r0 + (double)wp[2]*(double)rp;
    }
  }
  #pragma unroll
  for (int j = 0; j < 4; ++j)
    out[((size_t)b*NC + co0 + j)*T0 + lane] = lrelu_f((float)a[j]);
}

// ---------------- freq head: osc = W_freq . h ; split into l (square) and f (tanh map) ----------------
__global__ __launch_bounds__(256) void k_freq(const float* __restrict__ h, const float* __restrict__ w,
                                              const float* __restrict__ centers, const float* __restrict__ erbs,
                                              float* __restrict__ l_buf, float* __restrict__ f_buf){
  int b = blockIdx.x;
  int lane = threadIdx.x & 63, wv = threadIdx.x >> 6;
  int o0 = blockIdx.y*16 + wv*4;           // 0..255
  const float* hb = h + (size_t)b*NC*T0 + lane;
  double a[4] = {0.0,0.0,0.0,0.0};
  for (int ci = 0; ci < NC; ++ci){
    double v = (double)hb[(size_t)ci*T0];
    #pragma unroll
    for (int j = 0; j < 4; ++j) a[j] += v * (double)w[(size_t)(o0+j)*NC + ci];
  }
  #pragma unroll
  for (int j = 0; j < 4; ++j){
    int o = o0 + j;
    if (o < NOSC){
      l_buf[((size_t)b*NOSC + o)*T0 + lane] = (float)(a[j]*a[j]);
    } else {
      int oo = o - NOSC;
      double fv = (double)centers[oo] + tanh(a[j])*0.5*(double)erbs[oo];
      f_buf[((size_t)b*NOSC + oo)*T0 + lane] = (float)fv;
    }
  }
}

// ---------------- fused nearest-x2-upsample + k7 conv + bias + lrelu ----------------
// parity trick: out_even[s] = w0*i[s-2]+(w1+w2)*i[s-1]+(w3+w4)*i[s]+(w5+w6)*i[s+1]
//               out_odd[s]  = (w0+w1)*i[s-1]+(w2+w3)*i[s]+(w4+w5)*i[s+1]+w6*i[s+2]
// block: 4 waves; wave -> 4 consecutive co (wave-uniform weight loads); lane -> TPL outputs
template<int TPL>
__global__ __launch_bounds__(256) void k_nlconv(const float* __restrict__ in, const float* __restrict__ w,
                                                const float* __restrict__ bias, float* __restrict__ out, int Tin){
  const int Tout = 2*Tin;
  const int b = blockIdx.z;
  const int lane = threadIdx.x & 63;
  const int wv = threadIdx.x >> 6;
  const int co0 = blockIdx.y*16 + wv*4;
  const int t_blk = blockIdx.x * (64*TPL);
  const int base = t_blk/2 + lane*(TPL/2);
  constexpr int R = TPL/2 + 4;
  float acc[4][TPL];
  #pragma unroll
  for (int j4 = 0; j4 < 4; ++j4)
    #pragma unroll
    for (int j = 0; j < TPL; ++j) acc[j4][j] = 0.f;
  const float* inb = in + (size_t)b*NC*Tin;
  for (int ci = 0; ci < NC; ++ci){
    const float* row = inb + (size_t)ci*Tin;
    float r[R];
    #pragma unroll
    for (int m = 0; m < R; ++m){
      int p = base - 2 + m;
      r[m] = (p >= 0 && p < Tin) ? row[p] : 0.f;
    }
    #pragma unroll
    for (int j4 = 0; j4 < 4; ++j4){
      const float* wp = w + ((size_t)(co0+j4)*NC + ci)*7;
      float w0 = wp[0], w1 = wp[1], w2 = wp[2], w3 = wp[3], w4 = wp[4], w5 = wp[5], w6 = wp[6];
      float we0 = w0,    we1 = w1+w2, we2 = w3+w4, we3 = w5+w6;
      float wo0 = w0+w1, wo1 = w2+w3, wo2 = w4+w5, wo3 = w6;
      #pragma unroll
      for (int jj = 0; jj < TPL/2; ++jj){
        acc[j4][2*jj]   += we0*r[jj]   + we1*r[jj+1] + we2*r[jj+2] + we3*r[jj+3];
        acc[j4][2*jj+1] += wo0*r[jj+1] + wo1*r[jj+2] + wo2*r[jj+3] + wo3*r[jj+4];
      }
    }
  }
  #pragma unroll
  for (int j4 = 0; j4 < 4; ++j4){
    float bv = bias[co0+j4];
    float* ob = out + ((size_t)b*NC + co0 + j4)*Tout + t_blk + lane*TPL;
    #pragma unroll
    for (int j = 0; j < TPL; ++j) ob[j] = lrelu_f(acc[j4][j] + bv);
  }
}

// ---------------- noise-loudness output: n_l[b,k,j] = (sum_ci w[k,ci]*y3[b,ci,j])^2 ----------------
__global__ __launch_bounds__(256) void k_nlout(const float* __restrict__ y3, const float* __restrict__ w,
                                               float* __restrict__ n_l){
  int b = blockIdx.y;
  int j = blockIdx.x*256 + threadIdx.x;   // 0..1023
  float acc[17];
  #pragma unroll
  for (int k = 0; k < 17; ++k) acc[k] = 0.f;
  const float* yb = y3 + (size_t)b*NC*NFRAMES + j;
  for (int ci = 0; ci < NC; ++ci){
    float v = yb[(size_t)ci*NFRAMES];
    #pragma unroll
    for (int k = 0; k < 17; ++k) acc[k] += v * w[k*NC + ci];
  }
  #pragma unroll
  for (int k = 0; k < 17; ++k)
    n_l[((size_t)b*17 + k)*NFRAMES + j] = acc[k]*acc[k];
}

// ---------------- noise bank: per-frame DFT-filter (rfft*g -> irfft), norm='ortho' ----------------
__global__ __launch_bounds__(256) void k_noise(const float* __restrict__ noise, const float* __restrict__ n_l,
                                               float* __restrict__ frames){
  __shared__ float ctab[NWIN], stab[NWIN];
  int tid = threadIdx.x;
  if (tid < NWIN){
    double ang = (TWO_PI_D/NWIN)*tid;
    ctab[tid] = (float)cos(ang);
    stab[tid] = (float)sin(ang);
  }
  __syncthreads();
  int j = blockIdx.x*256 + tid;
  int b = blockIdx.y;
  const float* src = noise + ((size_t)b*NFRAMES + j)*NWIN;
  float nz[NWIN];
  #pragma unroll
  for (int n = 0; n < NWIN; ++n) nz[n] = src[n]*2.f - 1.f;
  float y[NWIN];
  #pragma unroll
  for (int n = 0; n < NWIN; ++n) y[n] = 0.f;
  const float* g = n_l + (size_t)b*17*NFRAMES + j;
  for (int k = 0; k < 17; ++k){
    float A = 0.f, Bv = 0.f;
    int m = 0;
    #pragma unroll
    for (int n = 0; n < NWIN; ++n){
      A  += nz[n]*ctab[m];
      Bv += nz[n]*stab[m];
      m = (m + k) & (NWIN-1);
    }
    float gk = g[(size_t)k*NFRAMES];
    float sc = (k == 0 || k == 16) ? 1.f : 2.f;
    float ga = sc*gk*A, gb = sc*gk*Bv;
    m = 0;
    #pragma unroll
    for (int n = 0; n < NWIN; ++n){
      y[n] += ga*ctab[m] + gb*stab[m];
      m = (m + k) & (NWIN-1);
    }
  }
  float* dst = frames + ((size_t)b*NFRAMES + j)*NWIN;
  #pragma unroll
  for (int n = 0; n < NWIN; ++n) dst[n] = y[n] * (1.f/NWIN);
}

// ---------------- oscillator phase: per-chunk sums (f64) of clipped, upsampled f ----------------
__global__ __launch_bounds__(256) void k_chunksum(const float* __restrict__ f_buf, double* __restrict__ cb){
  int idx = blockIdx.x*256 + threadIdx.x;      // NB*NOSC*NCHUNK
  int bo = idx & (NB*NOSC - 1);                // lane-varying
  int c  = idx >> 11;                          // uniform within block
  const float* f = f_buf + (size_t)bo*T0;
  double s = 0.0;
  int t0 = c*CHT;
  int cached = -1000; float f0 = 0.f, f1 = 0.f;
  for (int i = 0; i < CHT; ++i){
    int t = t0 + i;
    double coord = (t + 0.5)*(1.0/384.0) - 0.5;
    double fl = floor(coord);
    int lo = (int)fl;
    float wfr = (float)(coord - fl);
    if (lo != cached){
      cached = lo;
      int i0 = lo < 0 ? 0 : (lo > 63 ? 63 : lo);
      int i1 = lo+1 < 0 ? 0 : (lo+1 > 63 ? 63 : lo+1);
      f0 = f[i0]; f1 = f[i1];
    }
    float v = f0*(1.f - wfr) + f1*wfr;
    v = fminf(fmaxf(v, 20.f), 5512.5f);
    s += (double)v;
  }
  cb[(size_t)bo*NCHUNK + c] = s;
}

__global__ void k_scan(double* __restrict__ cb){
  int bo = blockIdx.x*64 + threadIdx.x;
  if (bo < NB*NOSC){
    double* p = cb + (size_t)bo*NCHUNK;
    double run = 0.0;
    for (int c = 0; c < NCHUNK; ++c){ double v = p[c]; p[c] = run; run += v; }
  }
}

// ---------------- oscillator bank + noise add: sig[b,t] ----------------
__global__ __launch_bounds__(128) void k_osc(const float* __restrict__ f_buf, const float* __restrict__ l_buf,
                                             const double* __restrict__ cb, const float* __restrict__ frames,
                                             float* __restrict__ sig){
  int c = blockIdx.x;       // chunk 0..95
  int b = blockIdx.y;
  int o = threadIdx.x;      // 0..127
  __shared__ float tile[64*129];
  __shared__ float harm[256];
  __shared__ float red[128];
  const float* f = f_buf + ((size_t)b*NOSC + o)*T0;
  const float* l = l_buf + ((size_t)b*NOSC + o)*T0;
  double sum = cb[((size_t)b*NOSC + o)*NCHUNK + c];
  int tstart = c*CHT;
  int cached = -1000; float f0 = 0.f, f1 = 0.f, l0 = 0.f, l1 = 0.f;
  for (int sub = 0; sub < 4; ++sub){
    for (int i = 0; i < 64; ++i){
      int t = tstart + sub*64 + i;
      double coord = (t + 0.5)*(1.0/384.0) - 0.5;
      double fl = floor(coord);
      int lo = (int)fl;
      float wfr = (float)(coord - fl);
      if (lo != cached){
        cached = lo;
        int i0 = lo < 0 ? 0 : (lo > 63 ? 63 : lo);
        int i1 = lo+1 < 0 ? 0 : (lo+1 > 63 ? 63 : lo+1);
        f0 = f[i0]; f1 = f[i1]; l0 = l[i0]; l1 = l[i1];
      }
      float fv = f0*(1.f - wfr) + f1*wfr;
      fv = fminf(fmaxf(fv, 20.f), 5512.5f);
      float lv = l0*(1.f - wfr) + l1*wfr;
      sum += (double)fv;
      double ph = sum * K_PHASE;
      double q = floor(ph * INV_2PI_D);
      float phw = (float)(ph - q*TWO_PI_D);
      tile[i*129 + o] = sinf(phw) * lv;
    }
    __syncthreads();
    {
      int row = o & 63, half = o >> 6;
      float s = 0.f;
      const float* tp = tile + row*129 + half*64;
      for (int j = 0; j < 64; ++j) s += tp[j];
      red[row*2 + half] = s;
    }
    __syncthreads();
    if (o < 64) harm[sub*64 + o] = red[o*2] + red[o*2 + 1];
    __syncthreads();
  }
  for (int i = o; i < CHT; i += 128){
    int t = tstart + i;
    float v = harm[i];
    int tn = t - NCROP;
    if (tn >= 0 && tn < NTOT){
      int j1 = tn >> 4, n1 = tn & 15;
      float nv = frames[((size_t)b*NFRAMES + j1)*NWIN + n1];
      if (j1 > 0) nv += frames[((size_t)b*NFRAMES + j1 - 1)*NWIN + n1 + 16];
      v += nv;
    }
    sig[(size_t)b*UPLEN + t] = v;
  }
}

// ---------------- per-batch max |sig| ----------------
__global__ __launch_bounds__(256) void k_max(const float* __restrict__ sig, float* __restrict__ maxa){
  int b = blockIdx.x;
  float m = 0.f;
  for (int i = threadIdx.x; i < UPLEN; i += 256)
    m = fmaxf(m, fabsf(sig[(size_t)b*UPLEN + i]));
  #pragma unroll
  for (int off = 32; off > 0; off >>= 1)
    m = fmaxf(m, __shfl_xor(m, off, 64));
  __shared__ float sm[4];
  if ((threadIdx.x & 63) == 0) sm[threadIdx.x >> 6] = m;
  __syncthreads();
  if (threadIdx.x == 0)
    maxa[b] = fmaxf(fmaxf(sm[0], sm[1]), fmaxf(sm[2], sm[3]));
}

// ---------------- normalize + crop ----------------
__global__ __launch_bounds__(256) void k_final(const float* __restrict__ sig, const float* __restrict__ maxa,
                                               float* __restrict__ out){
  int b = blockIdx.y;
  int i = blockIdx.x*256 + threadIdx.x;
  out[(size_t)b*NTOT + i] = sig[(size_t)b*UPLEN + NCROP + i] / (maxa[b] + 1e-8f);
}

extern "C" void kernel_launch(void* const* d_in, const int* in_sizes, int n_in,
                              void* d_out, int out_size, void* d_ws, size_t ws_size,
                              hipStream_t stream)
{
  (void)in_sizes; (void)n_in;
  const float* x     = (const float*)d_in[0];
  const float* w0    = (const float*)d_in[1];
  const float* w1    = (const float*)d_in[2];
  const float* w2    = (const float*)d_in[3];
  const float* w3    = (const float*)d_in[4];
  const float* wf    = (const float*)d_in[5];
  const float* wnl[4] = {(const float*)d_in[6], (const float*)d_in[8], (const float*)d_in[10], (const float*)d_in[12]};
  const float* bnl[4] = {(const float*)d_in[7], (const float*)d_in[9], (const float*)d_in[11], (const float*)d_in[13]};
  const float* wno   = (const float*)d_in[14];
  const float* noise = (const float*)d_in[15];
  float* out = (float*)d_out;

  char* base = (char*)d_ws;
  size_t off = 0;
  auto carve = [&](size_t bytes) -> void* {
    void* r = base + off;
    off += (bytes + 255) & ~(size_t)255;
    return r;
  };
  double* cbase  = (double*)carve(sizeof(double)*(size_t)NB*NOSC*NCHUNK);
  float* h_a     = (float*)carve(4ull*NB*NC*T0);
  float* h_b     = (float*)carve(4ull*NB*NC*T0);
  float* l_buf   = (float*)carve(4ull*NB*NOSC*T0);
  float* f_buf   = (float*)carve(4ull*NB*NOSC*T0);
  float* Vbuf    = (float*)carve(4ull*NB*NC*512);    // y0 then y2
  float* Ubuf    = (float*)carve(4ull*NB*NC*1024);   // y1 then y3
  float* n_l     = (float*)carve(4ull*NB*17*NFRAMES);
  float* frames  = (float*)carve(4ull*NB*NFRAMES*NWIN);
  float* sig     = (float*)carve(4ull*NB*UPLEN);
  float* maxa    = (float*)carve(4ull*NB);
  float* centers = (float*)carve(4ull*NOSC);
  float* erbs    = (float*)carve(4ull*NOSC);
  if (off > ws_size){
    fprintf(stderr, "kernel_launch: workspace too small: need %zu bytes, have %zu\n", off, ws_size);
    return;
  }
  if (out_size != NB*NTOT){
    fprintf(stderr, "kernel_launch: unexpected out_size %d (want %d)\n", out_size, NB*NTOT);
  }

  k_tables<<<1, 128, 0, stream>>>(centers, erbs);

  // main conv stack
  k_conv1<<<dim3(NB, 32), 256, 0, stream>>>(x, w0, h_a, 256, 512);
  k_conv3<<<dim3(NB, 32), 256, 0, stream>>>(h_a, w1, h_b);
  k_conv3<<<dim3(NB, 32), 256, 0, stream>>>(h_b, w2, h_a);
  k_conv3<<<dim3(NB, 32), 256, 0, stream>>>(h_a, w3, h_b);   // h = h_b

  // freq / loudness head
  k_freq<<<dim3(NB, 16), 256, 0, stream>>>(h_b, wf, centers, erbs, l_buf, f_buf);

  // noise-loudness branch (fused upsample-x2 + conv7 + bias + lrelu)
  k_nlconv<2><<<dim3(1, 32, NB), 256, 0, stream>>>(h_b,  wnl[0], bnl[0], Vbuf, 64);
  k_nlconv<4><<<dim3(1, 32, NB), 256, 0, stream>>>(Vbuf, wnl[1], bnl[1], Ubuf, 128);
  k_nlconv<8><<<dim3(1, 32, NB), 256, 0, stream>>>(Ubuf, wnl[2], bnl[2], Vbuf, 256);
  k_nlconv<8><<<dim3(2, 32, NB), 256, 0, stream>>>(Vbuf, wnl[3], bnl[3], Ubuf, 512);
  k_nlout<<<dim3(4, NB), 256, 0, stream>>>(Ubuf, wno, n_l);

  // noise bank
  k_noise<<<dim3(4, NB), 256, 0, stream>>>(noise, n_l, frames);

  // oscillator bank
  k_chunksum<<<dim3((NB*NOSC*NCHUNK)/256), 256, 0, stream>>>(f_buf, cbase);
  k_scan<<<dim3(32), 64, 0, stream>>>(cbase);
  k_osc<<<dim3(NCHUNK, NB), 128, 0, stream>>>(f_buf, l_buf, cbase, frames, sig);

  // normalize + crop
  k_max<<<dim3(NB), 256, 0, stream>>>(sig, maxa);
  k_final<<<dim3(NTOT/256, NB), 256, 0, stream>>>(sig, maxa, out);
}

// Round 2
// 3115.831 us; speedup vs baseline: 1.4475x; 1.4475x over previous
//
#include <hip/hip_runtime.h>
#include <cstdio>
#include <math.h>

#define NB 16
#define NC 512
#define T0 64
#define NOSC 128
#define UPLEN 24576
#define NTOT 16384
#define NWIN 32
#define NFRAMES 1024
#define NCROP 4096
#define NCHUNK 96
#define CHT 256

#define TWO_PI_D 6.283185307179586
#define INV_2PI_D 0.15915494309189535
#define K_PHASE (6.283185307179586/11025.0)

static __device__ __forceinline__ float lrelu_f(float x){ return x > 0.f ? x : 0.2f*x; }

// ---------------- tables: centers (np.geomspace(20, 5492.5, 128)) + erbs ----------------
__global__ void k_tables(float* __restrict__ centers, float* __restrict__ erbs){
  int o = threadIdx.x;
  if (o < NOSC){
    double lg0 = log10(20.0);
    double lg1 = log10(5492.5);
    double e = (o == NOSC-1) ? lg1 : (o*(lg1-lg0))/(double)(NOSC-1) + lg0;
    float c = (float)pow(10.0, e);
    centers[o] = c;
    erbs[o] = c*0.108f + 24.7f;
  }
}

// ---------------- pointwise conv + lrelu (f64 accumulate) ----------------
__global__ __launch_bounds__(256) void k_conv1(const float* __restrict__ in, const float* __restrict__ w,
                                               float* __restrict__ out, int Cin, int Cout){
  int b = blockIdx.x;
  int lane = threadIdx.x & 63, wv = threadIdx.x >> 6;
  int co0 = blockIdx.y*16 + wv*4;
  const float* inb = in + (size_t)b*Cin*T0 + lane;
  double a[4] = {0.0,0.0,0.0,0.0};
  for (int ci = 0; ci < Cin; ++ci){
    double v = (double)inb[(size_t)ci*T0];
    #pragma unroll
    for (int j = 0; j < 4; ++j) a[j] += v * (double)w[(size_t)(co0+j)*Cin + ci];
  }
  #pragma unroll
  for (int j = 0; j < 4; ++j)
    out[((size_t)b*Cout + co0 + j)*T0 + lane] = lrelu_f((float)a[j]);
}

// ---------------- k=3 conv + lrelu (pad 1, f64 accumulate) ----------------
__global__ __launch_bounds__(256) void k_conv3(const float* __restrict__ in, const float* __restrict__ w,
                                               float* __restrict__ out){
  int b = blockIdx.x;
  int lane = threadIdx.x & 63, wv = threadIdx.x >> 6;
  int co0 = blockIdx.y*16 + wv*4;
  const float* inb = in + (size_t)b*NC*T0;
  double a[4] = {0.0,0.0,0.0,0.0};
  for (int ci = 0; ci < NC; ++ci){
    const float* row = inb + (size_t)ci*T0;
    float rm = (lane > 0)  ? row[lane-1] : 0.f;
    float r0 = row[lane];
    float rp = (lane < 63) ? row[lane+1] : 0.f;
    #pragma unroll
    for (int j = 0; j < 4; ++j){
      const float* wp = w + ((size_t)(co0+j)*NC + ci)*3;
      a[j] += (double)wp[0]*(double)rm + (double)wp[1]*(double)r0 + (double)wp[2]*(double)rp;
    }
  }
  #pragma unroll
  for (int j = 0; j < 4; ++j)
    out[((size_t)b*NC + co0 + j)*T0 + lane] = lrelu_f((float)a[j]);
}

// ---------------- freq head ----------------
__global__ __launch_bounds__(256) void k_freq(const float* __restrict__ h, const float* __restrict__ w,
                                              const float* __restrict__ centers, const float* __restrict__ erbs,
                                              float* __restrict__ l_buf, float* __restrict__ f_buf){
  int b = blockIdx.x;
  int lane = threadIdx.x & 63, wv = threadIdx.x >> 6;
  int o0 = blockIdx.y*16 + wv*4;           // 0..255
  const float* hb = h + (size_t)b*NC*T0 + lane;
  double a[4] = {0.0,0.0,0.0,0.0};
  for (int ci = 0; ci < NC; ++ci){
    double v = (double)hb[(size_t)ci*T0];
    #pragma unroll
    for (int j = 0; j < 4; ++j) a[j] += v * (double)w[(size_t)(o0+j)*NC + ci];
  }
  #pragma unroll
  for (int j = 0; j < 4; ++j){
    int o = o0 + j;
    if (o < NOSC){
      l_buf[((size_t)b*NOSC + o)*T0 + lane] = (float)(a[j]*a[j]);
    } else {
      int oo = o - NOSC;
      double fv = (double)centers[oo] + tanh(a[j])*0.5*(double)erbs[oo];
      f_buf[((size_t)b*NOSC + oo)*T0 + lane] = (float)fv;
    }
  }
}

// ---------------- weight prep: collapse k7 upsample-conv into even/odd 4-tap pairs ----------------
// w [co][ci][7] -> w8 [co][ci][8] = {we0..we3, wo0..wo3}
__global__ __launch_bounds__(256) void k_prepw(const float* __restrict__ w, float* __restrict__ w8){
  int idx = blockIdx.x*256 + threadIdx.x;     // co*512+ci
  if (idx >= NC*NC) return;
  const float* wp = w + (size_t)idx*7;
  float w0 = wp[0], w1 = wp[1], w2 = wp[2], w3 = wp[3], w4 = wp[4], w5 = wp[5], w6 = wp[6];
  float* o = w8 + (size_t)idx*8;
  o[0] = w0;      o[1] = w1+w2;  o[2] = w3+w4;  o[3] = w5+w6;
  o[4] = w0+w1;   o[5] = w2+w3;  o[6] = w4+w5;  o[7] = w6;
}

// ---------------- fused nearest-x2-upsample + k7 conv + bias + lrelu (LDS-staged) ----------------
// block = 256 threads (4 waves); wave -> 4 co; block covers 16 co x TS input samples (2*TS outputs).
// grid: x = co-group (32), y = time block (Tin/TS), z = batch.
// LDS: CC input rows x (TS+8) floats, halo 4 left (aligned staging) / needs [-2,+2].
template<int TSL>
__global__ __launch_bounds__(256) void k_nlconv2(const float* __restrict__ in, const float* __restrict__ w8,
                                                 const float* __restrict__ bias, float* __restrict__ out, int Tin){
  constexpr int TS = 64*TSL;
  constexpr int RS = TS + 8;
  constexpr int CC = 32;
  __shared__ float lds[CC*RS];
  const int b = blockIdx.z;
  const int wv = threadIdx.x >> 6;
  const int lane = threadIdx.x & 63;
  const int co0 = blockIdx.x*16 + wv*4;
  const int TS0 = blockIdx.y*TS;
  const int tid = threadIdx.x;
  float acc[4][2*TSL];
  #pragma unroll
  for (int j4 = 0; j4 < 4; ++j4)
    #pragma unroll
    for (int j = 0; j < 2*TSL; ++j) acc[j4][j] = 0.f;
  const float* inb = in + (size_t)b*NC*Tin;
  for (int cc0 = 0; cc0 < NC; cc0 += CC){
    __syncthreads();
    // cooperative staging: rows cc0..cc0+CC-1, input positions TS0-4 .. TS0+TS+3 (zero outside)
    #pragma unroll 2
    for (int v = tid; v < CC*(RS/4); v += 256){
      int cl = v / (RS/4);
      int rv = (v - cl*(RS/4))*4;
      int p = TS0 - 4 + rv;                      // 4-aligned
      const float* row = inb + (size_t)(cc0+cl)*Tin;
      float4 val;
      if (p >= 0 && p+3 < Tin){
        val = *(const float4*)(row + p);
      } else {
        val.x = (p+0 >= 0 && p+0 < Tin) ? row[p+0] : 0.f;
        val.y = (p+1 >= 0 && p+1 < Tin) ? row[p+1] : 0.f;
        val.z = (p+2 >= 0 && p+2 < Tin) ? row[p+2] : 0.f;
        val.w = (p+3 >= 0 && p+3 < Tin) ? row[p+3] : 0.f;
      }
      *(float4*)(lds + cl*RS + rv) = val;
    }
    __syncthreads();
    #pragma unroll 4
    for (int cl = 0; cl < CC; ++cl){
      int ci = cc0 + cl;
      float rr[TSL+4];
      const float* lp = lds + cl*RS + lane*TSL + 2;   // rr[m] <-> input s0-2+m
      #pragma unroll
      for (int m = 0; m < TSL+4; ++m) rr[m] = lp[m];
      #pragma unroll
      for (int j4 = 0; j4 < 4; ++j4){
        const float4* wp = (const float4*)(w8 + ((size_t)(co0+j4)*NC + ci)*8);
        float4 we = wp[0], wo = wp[1];
        #pragma unroll
        for (int jj = 0; jj < TSL; ++jj){
          acc[j4][2*jj]   += we.x*rr[jj]   + we.y*rr[jj+1] + we.z*rr[jj+2] + we.w*rr[jj+3];
          acc[j4][2*jj+1] += wo.x*rr[jj+1] + wo.y*rr[jj+2] + wo.z*rr[jj+3] + wo.w*rr[jj+4];
        }
      }
    }
  }
  const int Tout = 2*Tin;
  #pragma unroll
  for (int j4 = 0; j4 < 4; ++j4){
    float bv = bias[co0+j4];
    float* ob = out + ((size_t)b*NC + co0 + j4)*Tout + 2*TS0 + lane*(2*TSL);
    #pragma unroll
    for (int j = 0; j < 2*TSL; ++j) ob[j] = lrelu_f(acc[j4][j] + bv);
  }
}

// ---------------- noise-loudness output ----------------
__global__ __launch_bounds__(256) void k_nlout(const float* __restrict__ y3, const float* __restrict__ w,
                                               float* __restrict__ n_l){
  int b = blockIdx.y;
  int j = blockIdx.x*256 + threadIdx.x;   // 0..1023
  float acc[17];
  #pragma unroll
  for (int k = 0; k < 17; ++k) acc[k] = 0.f;
  const float* yb = y3 + (size_t)b*NC*NFRAMES + j;
  for (int ci = 0; ci < NC; ++ci){
    float v = yb[(size_t)ci*NFRAMES];
    #pragma unroll
    for (int k = 0; k < 17; ++k) acc[k] += v * w[k*NC + ci];
  }
  #pragma unroll
  for (int k = 0; k < 17; ++k)
    n_l[((size_t)b*17 + k)*NFRAMES + j] = acc[k]*acc[k];
}

// ---------------- noise bank: per-frame DFT-filter ----------------
__global__ __launch_bounds__(256) void k_noise(const float* __restrict__ noise, const float* __restrict__ n_l,
                                               float* __restrict__ frames){
  __shared__ float ctab[NWIN], stab[NWIN];
  int tid = threadIdx.x;
  if (tid < NWIN){
    double ang = (TWO_PI_D/NWIN)*tid;
    ctab[tid] = (float)cos(ang);
    stab[tid] = (float)sin(ang);
  }
  __syncthreads();
  int j = blockIdx.x*256 + tid;
  int b = blockIdx.y;
  const float* src = noise + ((size_t)b*NFRAMES + j)*NWIN;
  float nz[NWIN];
  #pragma unroll
  for (int n = 0; n < NWIN; ++n) nz[n] = src[n]*2.f - 1.f;
  float y[NWIN];
  #pragma unroll
  for (int n = 0; n < NWIN; ++n) y[n] = 0.f;
  const float* g = n_l + (size_t)b*17*NFRAMES + j;
  for (int k = 0; k < 17; ++k){
    float A = 0.f, Bv = 0.f;
    int m = 0;
    #pragma unroll
    for (int n = 0; n < NWIN; ++n){
      A  += nz[n]*ctab[m];
      Bv += nz[n]*stab[m];
      m = (m + k) & (NWIN-1);
    }
    float gk = g[(size_t)k*NFRAMES];
    float sc = (k == 0 || k == 16) ? 1.f : 2.f;
    float ga = sc*gk*A, gb = sc*gk*Bv;
    m = 0;
    #pragma unroll
    for (int n = 0; n < NWIN; ++n){
      y[n] += ga*ctab[m] + gb*stab[m];
      m = (m + k) & (NWIN-1);
    }
  }
  float* dst = frames + ((size_t)b*NFRAMES + j)*NWIN;
  #pragma unroll
  for (int n = 0; n < NWIN; ++n) dst[n] = y[n] * (1.f/NWIN);
}

// ---------------- oscillator phase: per-chunk sums (f64) ----------------
__global__ __launch_bounds__(256) void k_chunksum(const float* __restrict__ f_buf, double* __restrict__ cb){
  int idx = blockIdx.x*256 + threadIdx.x;      // NB*NOSC*NCHUNK
  int bo = idx & (NB*NOSC - 1);
  int c  = idx >> 11;
  const float* f = f_buf + (size_t)bo*T0;
  double s = 0.0;
  int t0 = c*CHT;
  int cached = -1000; float f0 = 0.f, f1 = 0.f;
  for (int i = 0; i < CHT; ++i){
    int t = t0 + i;
    double coord = (t + 0.5)*(1.0/384.0) - 0.5;
    double fl = floor(coord);
    int lo = (int)fl;
    float wfr = (float)(coord - fl);
    if (lo != cached){
      cached = lo;
      int i0 = lo < 0 ? 0 : (lo > 63 ? 63 : lo);
      int i1 = lo+1 < 0 ? 0 : (lo+1 > 63 ? 63 : lo+1);
      f0 = f[i0]; f1 = f[i1];
    }
    float v = f0*(1.f - wfr) + f1*wfr;
    v = fminf(fmaxf(v, 20.f), 5512.5f);
    s += (double)v;
  }
  cb[(size_t)bo*NCHUNK + c] = s;
}

__global__ void k_scan(double* __restrict__ cb){
  int bo = blockIdx.x*64 + threadIdx.x;
  if (bo < NB*NOSC){
    double* p = cb + (size_t)bo*NCHUNK;
    double run = 0.0;
    for (int c = 0; c < NCHUNK; ++c){ double v = p[c]; p[c] = run; run += v; }
  }
}

// ---------------- oscillator bank + noise add ----------------
__global__ __launch_bounds__(128) void k_osc(const float* __restrict__ f_buf, const float* __restrict__ l_buf,
                                             const double* __restrict__ cb, const float* __restrict__ frames,
                                             float* __restrict__ sig){
  int c = blockIdx.x;
  int b = blockIdx.y;
  int o = threadIdx.x;
  __shared__ float tile[64*129];
  __shared__ float harm[256];
  __shared__ float red[128];
  const float* f = f_buf + ((size_t)b*NOSC + o)*T0;
  const float* l = l_buf + ((size_t)b*NOSC + o)*T0;
  double sum = cb[((size_t)b*NOSC + o)*NCHUNK + c];
  int tstart = c*CHT;
  int cached = -1000; float f0 = 0.f, f1 = 0.f, l0 = 0.f, l1 = 0.f;
  for (int sub = 0; sub < 4; ++sub){
    for (int i = 0; i < 64; ++i){
      int t = tstart + sub*64 + i;
      double coord = (t + 0.5)*(1.0/384.0) - 0.5;
      double fl = floor(coord);
      int lo = (int)fl;
      float wfr = (float)(coord - fl);
      if (lo != cached){
        cached = lo;
        int i0 = lo < 0 ? 0 : (lo > 63 ? 63 : lo);
        int i1 = lo+1 < 0 ? 0 : (lo+1 > 63 ? 63 : lo+1);
        f0 = f[i0]; f1 = f[i1]; l0 = l[i0]; l1 = l[i1];
      }
      float fv = f0*(1.f - wfr) + f1*wfr;
      fv = fminf(fmaxf(fv, 20.f), 5512.5f);
      float lv = l0*(1.f - wfr) + l1*wfr;
      sum += (double)fv;
      double ph = sum * K_PHASE;
      double q = floor(ph * INV_2PI_D);
      float phw = (float)(ph - q*TWO_PI_D);
      tile[i*129 + o] = sinf(phw) * lv;
    }
    __syncthreads();
    {
      int row = o & 63, half = o >> 6;
      float s = 0.f;
      const float* tp = tile + row*129 + half*64;
      for (int j = 0; j < 64; ++j) s += tp[j];
      red[row*2 + half] = s;
    }
    __syncthreads();
    if (o < 64) harm[sub*64 + o] = red[o*2] + red[o*2 + 1];
    __syncthreads();
  }
  for (int i = o; i < CHT; i += 128){
    int t = tstart + i;
    float v = harm[i];
    int tn = t - NCROP;
    if (tn >= 0 && tn < NTOT){
      int j1 = tn >> 4, n1 = tn & 15;
      float nv = frames[((size_t)b*NFRAMES + j1)*NWIN + n1];
      if (j1 > 0) nv += frames[((size_t)b*NFRAMES + j1 - 1)*NWIN + n1 + 16];
      v += nv;
    }
    sig[(size_t)b*UPLEN + t] = v;
  }
}

// ---------------- per-batch max |sig| ----------------
__global__ __launch_bounds__(256) void k_max(const float* __restrict__ sig, float* __restrict__ maxa){
  int b = blockIdx.x;
  float m = 0.f;
  for (int i = threadIdx.x; i < UPLEN; i += 256)
    m = fmaxf(m, fabsf(sig[(size_t)b*UPLEN + i]));
  #pragma unroll
  for (int off = 32; off > 0; off >>= 1)
    m = fmaxf(m, __shfl_xor(m, off, 64));
  __shared__ float sm[4];
  if ((threadIdx.x & 63) == 0) sm[threadIdx.x >> 6] = m;
  __syncthreads();
  if (threadIdx.x == 0)
    maxa[b] = fmaxf(fmaxf(sm[0], sm[1]), fmaxf(sm[2], sm[3]));
}

// ---------------- normalize + crop ----------------
__global__ __launch_bounds__(256) void k_final(const float* __restrict__ sig, const float* __restrict__ maxa,
                                               float* __restrict__ out){
  int b = blockIdx.y;
  int i = blockIdx.x*256 + threadIdx.x;
  out[(size_t)b*NTOT + i] = sig[(size_t)b*UPLEN + NCROP + i] / (maxa[b] + 1e-8f);
}

extern "C" void kernel_launch(void* const* d_in, const int* in_sizes, int n_in,
                              void* d_out, int out_size, void* d_ws, size_t ws_size,
                              hipStream_t stream)
{
  (void)in_sizes; (void)n_in;
  const float* x     = (const float*)d_in[0];
  const float* w0    = (const float*)d_in[1];
  const float* w1    = (const float*)d_in[2];
  const float* w2    = (const float*)d_in[3];
  const float* w3    = (const float*)d_in[4];
  const float* wf    = (const float*)d_in[5];
  const float* wnl[4] = {(const float*)d_in[6], (const float*)d_in[8], (const float*)d_in[10], (const float*)d_in[12]};
  const float* bnl[4] = {(const float*)d_in[7], (const float*)d_in[9], (const float*)d_in[11], (const float*)d_in[13]};
  const float* wno   = (const float*)d_in[14];
  const float* noise = (const float*)d_in[15];
  float* out = (float*)d_out;

  char* base = (char*)d_ws;
  size_t off = 0;
  auto carve = [&](size_t bytes) -> void* {
    void* r = base + off;
    off += (bytes + 255) & ~(size_t)255;
    return r;
  };
  double* cbase  = (double*)carve(sizeof(double)*(size_t)NB*NOSC*NCHUNK);
  float* h_a     = (float*)carve(4ull*NB*NC*T0);
  float* h_b     = (float*)carve(4ull*NB*NC*T0);
  float* l_buf   = (float*)carve(4ull*NB*NOSC*T0);
  float* f_buf   = (float*)carve(4ull*NB*NOSC*T0);
  float* Vbuf    = (float*)carve(4ull*NB*NC*512);    // y0 then y2
  float* Ubuf    = (float*)carve(4ull*NB*NC*1024);   // y1 then y3
  float* n_l     = (float*)carve(4ull*NB*17*NFRAMES);
  float* frames  = (float*)carve(4ull*NB*NFRAMES*NWIN);
  float* sig     = (float*)carve(4ull*NB*UPLEN);
  float* maxa    = (float*)carve(4ull*NB);
  float* centers = (float*)carve(4ull*NOSC);
  float* erbs    = (float*)carve(4ull*NOSC);
  float* w8buf   = (float*)carve(4ull*NC*NC*8);      // collapsed weights, reused per layer
  if (off > ws_size){
    fprintf(stderr, "kernel_launch: workspace too small: need %zu bytes, have %zu\n", off, ws_size);
    return;
  }
  if (out_size != NB*NTOT){
    fprintf(stderr, "kernel_launch: unexpected out_size %d (want %d)\n", out_size, NB*NTOT);
  }

  k_tables<<<1, 128, 0, stream>>>(centers, erbs);

  // main conv stack
  k_conv1<<<dim3(NB, 32), 256, 0, stream>>>(x, w0, h_a, 256, 512);
  k_conv3<<<dim3(NB, 32), 256, 0, stream>>>(h_a, w1, h_b);
  k_conv3<<<dim3(NB, 32), 256, 0, stream>>>(h_b, w2, h_a);
  k_conv3<<<dim3(NB, 32), 256, 0, stream>>>(h_a, w3, h_b);   // h = h_b

  // freq / loudness head
  k_freq<<<dim3(NB, 16), 256, 0, stream>>>(h_b, wf, centers, erbs, l_buf, f_buf);

  // noise-loudness branch (LDS-staged fused upsample-x2 + conv7 + bias + lrelu)
  const int PREP_BLKS = (NC*NC + 255)/256;
  k_prepw<<<dim3(PREP_BLKS), 256, 0, stream>>>(wnl[0], w8buf);
  k_nlconv2<1><<<dim3(32, 1, NB), 256, 0, stream>>>(h_b,  w8buf, bnl[0], Vbuf, 64);
  k_prepw<<<dim3(PREP_BLKS), 256, 0, stream>>>(wnl[1], w8buf);
  k_nlconv2<2><<<dim3(32, 1, NB), 256, 0, stream>>>(Vbuf, w8buf, bnl[1], Ubuf, 128);
  k_prepw<<<dim3(PREP_BLKS), 256, 0, stream>>>(wnl[2], w8buf);
  k_nlconv2<2><<<dim3(32, 2, NB), 256, 0, stream>>>(Ubuf, w8buf, bnl[2], Vbuf, 256);
  k_prepw<<<dim3(PREP_BLKS), 256, 0, stream>>>(wnl[3], w8buf);
  k_nlconv2<4><<<dim3(32, 2, NB), 256, 0, stream>>>(Vbuf, w8buf, bnl[3], Ubuf, 512);
  k_nlout<<<dim3(4, NB), 256, 0, stream>>>(Ubuf, wno, n_l);

  // noise bank
  k_noise<<<dim3(4, NB), 256, 0, stream>>>(noise, n_l, frames);

  // oscillator bank
  k_chunksum<<<dim3((NB*NOSC*NCHUNK)/256), 256, 0, stream>>>(f_buf, cbase);
  k_scan<<<dim3(32), 64, 0, stream>>>(cbase);
  k_osc<<<dim3(NCHUNK, NB), 128, 0, stream>>>(f_buf, l_buf, cbase, frames, sig);

  // normalize + crop
  k_max<<<dim3(NB), 256, 0, stream>>>(sig, maxa);
  k_final<<<dim3(NTOT/256, NB), 256, 0, stream>>>(sig, maxa, out);
}

// Round 3
// 2872.578 us; speedup vs baseline: 1.5701x; 1.0847x over previous
//
#include <hip/hip_runtime.h>
#include <cstdio>
#include <math.h>

#define NB 16
#define NC 512
#define T0 64
#define NOSC 128
#define UPLEN 24576
#define NTOT 16384
#define NWIN 32
#define NFRAMES 1024
#define NCROP 4096
#define NCHUNK 96
#define CHT 256

#define TWO_PI_D 6.283185307179586
#define INV_2PI_D 0.15915494309189535
#define K_PHASE (6.283185307179586/11025.0)

static __device__ __forceinline__ float lrelu_f(float x){ return x > 0.f ? x : 0.2f*x; }

// ---------------- tables: centers (np.geomspace(20, 5492.5, 128)) + erbs ----------------
__global__ void k_tables(float* __restrict__ centers, float* __restrict__ erbs){
  int o = threadIdx.x;
  if (o < NOSC){
    double lg0 = log10(20.0);
    double lg1 = log10(5492.5);
    double e = (o == NOSC-1) ? lg1 : (o*(lg1-lg0))/(double)(NOSC-1) + lg0;
    float c = (float)pow(10.0, e);
    centers[o] = c;
    erbs[o] = c*0.108f + 24.7f;
  }
}

// ---------------- pointwise conv + lrelu (f64 accumulate) ----------------
__global__ __launch_bounds__(256) void k_conv1(const float* __restrict__ in, const float* __restrict__ w,
                                               float* __restrict__ out, int Cin, int Cout){
  int b = blockIdx.x;
  int lane = threadIdx.x & 63, wv = threadIdx.x >> 6;
  int co0 = blockIdx.y*16 + wv*4;
  const float* inb = in + (size_t)b*Cin*T0 + lane;
  double a[4] = {0.0,0.0,0.0,0.0};
  for (int ci = 0; ci < Cin; ++ci){
    double v = (double)inb[(size_t)ci*T0];
    #pragma unroll
    for (int j = 0; j < 4; ++j) a[j] += v * (double)w[(size_t)(co0+j)*Cin + ci];
  }
  #pragma unroll
  for (int j = 0; j < 4; ++j)
    out[((size_t)b*Cout + co0 + j)*T0 + lane] = lrelu_f((float)a[j]);
}

// ---------------- k=3 conv + lrelu (pad 1, f64 accumulate, shfl neighbors) ----------------
__global__ __launch_bounds__(256) void k_conv3(const float* __restrict__ in, const float* __restrict__ w,
                                               float* __restrict__ out){
  int b = blockIdx.x;
  int lane = threadIdx.x & 63, wv = threadIdx.x >> 6;
  int co0 = blockIdx.y*16 + wv*4;
  const float* inb = in + (size_t)b*NC*T0;
  double a0[4] = {0.0,0.0,0.0,0.0};
  double a1[4] = {0.0,0.0,0.0,0.0};
  for (int ci = 0; ci < NC; ci += 2){
    float v0 = inb[(size_t)ci*T0 + lane];
    float v1 = inb[(size_t)(ci+1)*T0 + lane];
    float v0m = __shfl_up(v0, 1);  float v1m = __shfl_up(v1, 1);
    float v0p = __shfl_down(v0, 1);float v1p = __shfl_down(v1, 1);
    if (lane == 0){ v0m = 0.f; v1m = 0.f; }
    if (lane == 63){ v0p = 0.f; v1p = 0.f; }
    #pragma unroll
    for (int j = 0; j < 4; ++j){
      const float* wp0 = w + ((size_t)(co0+j)*NC + ci)*3;
      a0[j] += (double)wp0[0]*(double)v0m + (double)wp0[1]*(double)v0 + (double)wp0[2]*(double)v0p;
      a1[j] += (double)wp0[3]*(double)v1m + (double)wp0[4]*(double)v1 + (double)wp0[5]*(double)v1p;
    }
  }
  #pragma unroll
  for (int j = 0; j < 4; ++j)
    out[((size_t)b*NC + co0 + j)*T0 + lane] = lrelu_f((float)(a0[j] + a1[j]));
}

// ---------------- freq head ----------------
__global__ __launch_bounds__(256) void k_freq(const float* __restrict__ h, const float* __restrict__ w,
                                              const float* __restrict__ centers, const float* __restrict__ erbs,
                                              float* __restrict__ l_buf, float* __restrict__ f_buf){
  int b = blockIdx.x;
  int lane = threadIdx.x & 63, wv = threadIdx.x >> 6;
  int o0 = blockIdx.y*16 + wv*4;           // 0..255
  const float* hb = h + (size_t)b*NC*T0 + lane;
  double a[4] = {0.0,0.0,0.0,0.0};
  for (int ci = 0; ci < NC; ++ci){
    double v = (double)hb[(size_t)ci*T0];
    #pragma unroll
    for (int j = 0; j < 4; ++j) a[j] += v * (double)w[(size_t)(o0+j)*NC + ci];
  }
  #pragma unroll
  for (int j = 0; j < 4; ++j){
    int o = o0 + j;
    if (o < NOSC){
      l_buf[((size_t)b*NOSC + o)*T0 + lane] = (float)(a[j]*a[j]);
    } else {
      int oo = o - NOSC;
      double fv = (double)centers[oo] + tanh(a[j])*0.5*(double)erbs[oo];
      f_buf[((size_t)b*NOSC + oo)*T0 + lane] = (float)fv;
    }
  }
}

// ---------------- weight prep: collapse k7 upsample-conv into even/odd 4-tap pairs ----------------
__global__ __launch_bounds__(256) void k_prepw(const float* __restrict__ w, float* __restrict__ w8){
  int idx = blockIdx.x*256 + threadIdx.x;     // co*512+ci
  if (idx >= NC*NC) return;
  const float* wp = w + (size_t)idx*7;
  float w0 = wp[0], w1 = wp[1], w2 = wp[2], w3 = wp[3], w4 = wp[4], w5 = wp[5], w6 = wp[6];
  float* o = w8 + (size_t)idx*8;
  o[0] = w0;      o[1] = w1+w2;  o[2] = w3+w4;  o[3] = w5+w6;
  o[4] = w0+w1;   o[5] = w2+w3;  o[6] = w4+w5;  o[7] = w6;
}

// ---------------- fused nearest-x2-upsample + k7 conv + bias + lrelu (LDS-staged) ----------------
// TSL=2: lane stride 8B in LDS -> 2-way bank aliasing (free); 3x aligned ds_read_b64.
// TSL=1: lane stride 4B -> conflict-free scalar reads.
template<int TSL>
__global__ __launch_bounds__(256) void k_nlconv2(const float* __restrict__ in, const float* __restrict__ w8,
                                                 const float* __restrict__ bias, float* __restrict__ out, int Tin){
  constexpr int TS = 64*TSL;
  constexpr int RS = TS + 8;
  constexpr int CC = 32;
  __shared__ float lds[CC*RS];
  const int b = blockIdx.z;
  const int wv = threadIdx.x >> 6;
  const int lane = threadIdx.x & 63;
  const int co0 = blockIdx.x*16 + wv*4;
  const int TS0 = blockIdx.y*TS;
  const int tid = threadIdx.x;
  float acc[4][2*TSL];
  #pragma unroll
  for (int j4 = 0; j4 < 4; ++j4)
    #pragma unroll
    for (int j = 0; j < 2*TSL; ++j) acc[j4][j] = 0.f;
  const float* inb = in + (size_t)b*NC*Tin;
  for (int cc0 = 0; cc0 < NC; cc0 += CC){
    __syncthreads();
    // cooperative staging: rows cc0..cc0+CC-1, input positions TS0-4 .. TS0+TS+3 (zero outside)
    #pragma unroll 2
    for (int v = tid; v < CC*(RS/4); v += 256){
      int cl = v / (RS/4);
      int rv = (v - cl*(RS/4))*4;
      int p = TS0 - 4 + rv;                      // 4-aligned
      const float* row = inb + (size_t)(cc0+cl)*Tin;
      float4 val;
      if (p >= 0 && p+3 < Tin){
        val = *(const float4*)(row + p);
      } else {
        val.x = (p+0 >= 0 && p+0 < Tin) ? row[p+0] : 0.f;
        val.y = (p+1 >= 0 && p+1 < Tin) ? row[p+1] : 0.f;
        val.z = (p+2 >= 0 && p+2 < Tin) ? row[p+2] : 0.f;
        val.w = (p+3 >= 0 && p+3 < Tin) ? row[p+3] : 0.f;
      }
      *(float4*)(lds + cl*RS + rv) = val;
    }
    __syncthreads();
    // lds index i <-> input position TS0-4+i ; lane needs input TS0+lane*TSL-2+m, m=0..TSL+3
    //                                           = lds idx lane*TSL+2+m
    #pragma unroll 4
    for (int cl = 0; cl < CC; ++cl){
      int ci = cc0 + cl;
      float rr[TSL+4];
      if constexpr (TSL == 2){
        const float2* lp2 = (const float2*)(lds + cl*RS + lane*2 + 2);  // 8B-aligned
        float2 q0 = lp2[0], q1 = lp2[1], q2 = lp2[2];
        rr[0] = q0.x; rr[1] = q0.y; rr[2] = q1.x; rr[3] = q1.y; rr[4] = q2.x; rr[5] = q2.y;
      } else {
        const float* lp = lds + cl*RS + lane + 2;
        #pragma unroll
        for (int m = 0; m < TSL+4; ++m) rr[m] = lp[m];
      }
      #pragma unroll
      for (int j4 = 0; j4 < 4; ++j4){
        const float4* wp = (const float4*)(w8 + ((size_t)(co0+j4)*NC + ci)*8);
        float4 we = wp[0], wo = wp[1];
        #pragma unroll
        for (int jj = 0; jj < TSL; ++jj){
          acc[j4][2*jj]   += we.x*rr[jj]   + we.y*rr[jj+1] + we.z*rr[jj+2] + we.w*rr[jj+3];
          acc[j4][2*jj+1] += wo.x*rr[jj+1] + wo.y*rr[jj+2] + wo.z*rr[jj+3] + wo.w*rr[jj+4];
        }
      }
    }
  }
  const int Tout = 2*Tin;
  #pragma unroll
  for (int j4 = 0; j4 < 4; ++j4){
    float bv = bias[co0+j4];
    float* ob = out + ((size_t)b*NC + co0 + j4)*Tout + 2*TS0 + lane*(2*TSL);
    #pragma unroll
    for (int j = 0; j < 2*TSL; ++j) ob[j] = lrelu_f(acc[j4][j] + bv);
  }
}

// ---------------- noise-loudness output ----------------
__global__ __launch_bounds__(256) void k_nlout(const float* __restrict__ y3, const float* __restrict__ w,
                                               float* __restrict__ n_l){
  int b = blockIdx.y;
  int j = blockIdx.x*256 + threadIdx.x;   // 0..1023
  float acc[17];
  #pragma unroll
  for (int k = 0; k < 17; ++k) acc[k] = 0.f;
  const float* yb = y3 + (size_t)b*NC*NFRAMES + j;
  for (int ci = 0; ci < NC; ++ci){
    float v = yb[(size_t)ci*NFRAMES];
    #pragma unroll
    for (int k = 0; k < 17; ++k) acc[k] += v * w[k*NC + ci];
  }
  #pragma unroll
  for (int k = 0; k < 17; ++k)
    n_l[((size_t)b*17 + k)*NFRAMES + j] = acc[k]*acc[k];
}

// ---------------- noise bank: per-frame DFT-filter ----------------
__global__ __launch_bounds__(256) void k_noise(const float* __restrict__ noise, const float* __restrict__ n_l,
                                               float* __restrict__ frames){
  __shared__ float ctab[NWIN], stab[NWIN];
  int tid = threadIdx.x;
  if (tid < NWIN){
    double ang = (TWO_PI_D/NWIN)*tid;
    ctab[tid] = (float)cos(ang);
    stab[tid] = (float)sin(ang);
  }
  __syncthreads();
  int j = blockIdx.x*256 + tid;
  int b = blockIdx.y;
  const float* src = noise + ((size_t)b*NFRAMES + j)*NWIN;
  float nz[NWIN];
  #pragma unroll
  for (int n = 0; n < NWIN; ++n) nz[n] = src[n]*2.f - 1.f;
  float y[NWIN];
  #pragma unroll
  for (int n = 0; n < NWIN; ++n) y[n] = 0.f;
  const float* g = n_l + (size_t)b*17*NFRAMES + j;
  for (int k = 0; k < 17; ++k){
    float A = 0.f, Bv = 0.f;
    int m = 0;
    #pragma unroll
    for (int n = 0; n < NWIN; ++n){
      A  += nz[n]*ctab[m];
      Bv += nz[n]*stab[m];
      m = (m + k) & (NWIN-1);
    }
    float gk = g[(size_t)k*NFRAMES];
    float sc = (k == 0 || k == 16) ? 1.f : 2.f;
    float ga = sc*gk*A, gb = sc*gk*Bv;
    m = 0;
    #pragma unroll
    for (int n = 0; n < NWIN; ++n){
      y[n] += ga*ctab[m] + gb*stab[m];
      m = (m + k) & (NWIN-1);
    }
  }
  float* dst = frames + ((size_t)b*NFRAMES + j)*NWIN;
  #pragma unroll
  for (int n = 0; n < NWIN; ++n) dst[n] = y[n] * (1.f/NWIN);
}

// ---------------- oscillator phase: per-chunk sums (f64) ----------------
__global__ __launch_bounds__(256) void k_chunksum(const float* __restrict__ f_buf, double* __restrict__ cb){
  int idx = blockIdx.x*256 + threadIdx.x;      // NB*NOSC*NCHUNK
  int bo = idx & (NB*NOSC - 1);
  int c  = idx >> 11;
  const float* f = f_buf + (size_t)bo*T0;
  double s = 0.0;
  int t0 = c*CHT;
  int cached = -1000; float f0 = 0.f, f1 = 0.f;
  for (int i = 0; i < CHT; ++i){
    int t = t0 + i;
    double coord = (t + 0.5)*(1.0/384.0) - 0.5;
    double fl = floor(coord);
    int lo = (int)fl;
    float wfr = (float)(coord - fl);
    if (lo != cached){
      cached = lo;
      int i0 = lo < 0 ? 0 : (lo > 63 ? 63 : lo);
      int i1 = lo+1 < 0 ? 0 : (lo+1 > 63 ? 63 : lo+1);
      f0 = f[i0]; f1 = f[i1];
    }
    float v = f0*(1.f - wfr) + f1*wfr;
    v = fminf(fmaxf(v, 20.f), 5512.5f);
    s += (double)v;
  }
  cb[(size_t)bo*NCHUNK + c] = s;
}

__global__ void k_scan(double* __restrict__ cb){
  int bo = blockIdx.x*64 + threadIdx.x;
  if (bo < NB*NOSC){
    double* p = cb + (size_t)bo*NCHUNK;
    double run = 0.0;
    for (int c = 0; c < NCHUNK; ++c){ double v = p[c]; p[c] = run; run += v; }
  }
}

// ---------------- oscillator bank + noise add ----------------
__global__ __launch_bounds__(128) void k_osc(const float* __restrict__ f_buf, const float* __restrict__ l_buf,
                                             const double* __restrict__ cb, const float* __restrict__ frames,
                                             float* __restrict__ sig){
  int c = blockIdx.x;
  int b = blockIdx.y;
  int o = threadIdx.x;
  __shared__ float tile[64*129];
  __shared__ float harm[256];
  __shared__ float red[128];
  const float* f = f_buf + ((size_t)b*NOSC + o)*T0;
  const float* l = l_buf + ((size_t)b*NOSC + o)*T0;
  double sum = cb[((size_t)b*NOSC + o)*NCHUNK + c];
  int tstart = c*CHT;
  int cached = -1000; float f0 = 0.f, f1 = 0.f, l0 = 0.f, l1 = 0.f;
  for (int sub = 0; sub < 4; ++sub){
    for (int i = 0; i < 64; ++i){
      int t = tstart + sub*64 + i;
      double coord = (t + 0.5)*(1.0/384.0) - 0.5;
      double fl = floor(coord);
      int lo = (int)fl;
      float wfr = (float)(coord - fl);
      if (lo != cached){
        cached = lo;
        int i0 = lo < 0 ? 0 : (lo > 63 ? 63 : lo);
        int i1 = lo+1 < 0 ? 0 : (lo+1 > 63 ? 63 : lo+1);
        f0 = f[i0]; f1 = f[i1]; l0 = l[i0]; l1 = l[i1];
      }
      float fv = f0*(1.f - wfr) + f1*wfr;
      fv = fminf(fmaxf(fv, 20.f), 5512.5f);
      float lv = l0*(1.f - wfr) + l1*wfr;
      sum += (double)fv;
      double ph = sum * K_PHASE;
      double q = floor(ph * INV_2PI_D);
      float phw = (float)(ph - q*TWO_PI_D);
      tile[i*129 + o] = sinf(phw) * lv;
    }
    __syncthreads();
    {
      int row = o & 63, half = o >> 6;
      float s = 0.f;
      const float* tp = tile + row*129 + half*64;
      for (int j = 0; j < 64; ++j) s += tp[j];
      red[row*2 + half] = s;
    }
    __syncthreads();
    if (o < 64) harm[sub*64 + o] = red[o*2] + red[o*2 + 1];
    __syncthreads();
  }
  for (int i = o; i < CHT; i += 128){
    int t = tstart + i;
    float v = harm[i];
    int tn = t - NCROP;
    if (tn >= 0 && tn < NTOT){
      int j1 = tn >> 4, n1 = tn & 15;
      float nv = frames[((size_t)b*NFRAMES + j1)*NWIN + n1];
      if (j1 > 0) nv += frames[((size_t)b*NFRAMES + j1 - 1)*NWIN + n1 + 16];
      v += nv;
    }
    sig[(size_t)b*UPLEN + t] = v;
  }
}

// ---------------- per-batch max |sig| ----------------
__global__ __launch_bounds__(256) void k_max(const float* __restrict__ sig, float* __restrict__ maxa){
  int b = blockIdx.x;
  float m = 0.f;
  for (int i = threadIdx.x; i < UPLEN; i += 256)
    m = fmaxf(m, fabsf(sig[(size_t)b*UPLEN + i]));
  #pragma unroll
  for (int off = 32; off > 0; off >>= 1)
    m = fmaxf(m, __shfl_xor(m, off, 64));
  __shared__ float sm[4];
  if ((threadIdx.x & 63) == 0) sm[threadIdx.x >> 6] = m;
  __syncthreads();
  if (threadIdx.x == 0)
    maxa[b] = fmaxf(fmaxf(sm[0], sm[1]), fmaxf(sm[2], sm[3]));
}

// ---------------- normalize + crop ----------------
__global__ __launch_bounds__(256) void k_final(const float* __restrict__ sig, const float* __restrict__ maxa,
                                               float* __restrict__ out){
  int b = blockIdx.y;
  int i = blockIdx.x*256 + threadIdx.x;
  out[(size_t)b*NTOT + i] = sig[(size_t)b*UPLEN + NCROP + i] / (maxa[b] + 1e-8f);
}

extern "C" void kernel_launch(void* const* d_in, const int* in_sizes, int n_in,
                              void* d_out, int out_size, void* d_ws, size_t ws_size,
                              hipStream_t stream)
{
  (void)in_sizes; (void)n_in;
  const float* x     = (const float*)d_in[0];
  const float* w0    = (const float*)d_in[1];
  const float* w1    = (const float*)d_in[2];
  const float* w2    = (const float*)d_in[3];
  const float* w3    = (const float*)d_in[4];
  const float* wf    = (const float*)d_in[5];
  const float* wnl[4] = {(const float*)d_in[6], (const float*)d_in[8], (const float*)d_in[10], (const float*)d_in[12]};
  const float* bnl[4] = {(const float*)d_in[7], (const float*)d_in[9], (const float*)d_in[11], (const float*)d_in[13]};
  const float* wno   = (const float*)d_in[14];
  const float* noise = (const float*)d_in[15];
  float* out = (float*)d_out;

  char* base = (char*)d_ws;
  size_t off = 0;
  auto carve = [&](size_t bytes) -> void* {
    void* r = base + off;
    off += (bytes + 255) & ~(size_t)255;
    return r;
  };
  double* cbase  = (double*)carve(sizeof(double)*(size_t)NB*NOSC*NCHUNK);
  float* h_a     = (float*)carve(4ull*NB*NC*T0);
  float* h_b     = (float*)carve(4ull*NB*NC*T0);
  float* l_buf   = (float*)carve(4ull*NB*NOSC*T0);
  float* f_buf   = (float*)carve(4ull*NB*NOSC*T0);
  float* Vbuf    = (float*)carve(4ull*NB*NC*512);    // y0 then y2
  float* Ubuf    = (float*)carve(4ull*NB*NC*1024);   // y1 then y3
  float* n_l     = (float*)carve(4ull*NB*17*NFRAMES);
  float* frames  = (float*)carve(4ull*NB*NFRAMES*NWIN);
  float* sig     = (float*)carve(4ull*NB*UPLEN);
  float* maxa    = (float*)carve(4ull*NB);
  float* centers = (float*)carve(4ull*NOSC);
  float* erbs    = (float*)carve(4ull*NOSC);
  float* w8buf   = (float*)carve(4ull*NC*NC*8);      // collapsed weights, reused per layer
  if (off > ws_size){
    fprintf(stderr, "kernel_launch: workspace too small: need %zu bytes, have %zu\n", off, ws_size);
    return;
  }
  if (out_size != NB*NTOT){
    fprintf(stderr, "kernel_launch: unexpected out_size %d (want %d)\n", out_size, NB*NTOT);
  }

  k_tables<<<1, 128, 0, stream>>>(centers, erbs);

  // main conv stack
  k_conv1<<<dim3(NB, 32), 256, 0, stream>>>(x, w0, h_a, 256, 512);
  k_conv3<<<dim3(NB, 32), 256, 0, stream>>>(h_a, w1, h_b);
  k_conv3<<<dim3(NB, 32), 256, 0, stream>>>(h_b, w2, h_a);
  k_conv3<<<dim3(NB, 32), 256, 0, stream>>>(h_a, w3, h_b);   // h = h_b

  // freq / loudness head
  k_freq<<<dim3(NB, 16), 256, 0, stream>>>(h_b, wf, centers, erbs, l_buf, f_buf);

  // noise-loudness branch (LDS-staged fused upsample-x2 + conv7 + bias + lrelu)
  const int PREP_BLKS = (NC*NC + 255)/256;
  k_prepw<<<dim3(PREP_BLKS), 256, 0, stream>>>(wnl[0], w8buf);
  k_nlconv2<1><<<dim3(32, 1, NB), 256, 0, stream>>>(h_b,  w8buf, bnl[0], Vbuf, 64);
  k_prepw<<<dim3(PREP_BLKS), 256, 0, stream>>>(wnl[1], w8buf);
  k_nlconv2<2><<<dim3(32, 1, NB), 256, 0, stream>>>(Vbuf, w8buf, bnl[1], Ubuf, 128);
  k_prepw<<<dim3(PREP_BLKS), 256, 0, stream>>>(wnl[2], w8buf);
  k_nlconv2<2><<<dim3(32, 2, NB), 256, 0, stream>>>(Ubuf, w8buf, bnl[2], Vbuf, 256);
  k_prepw<<<dim3(PREP_BLKS), 256, 0, stream>>>(wnl[3], w8buf);
  k_nlconv2<2><<<dim3(32, 4, NB), 256, 0, stream>>>(Vbuf, w8buf, bnl[3], Ubuf, 512);
  k_nlout<<<dim3(4, NB), 256, 0, stream>>>(Ubuf, wno, n_l);

  // noise bank
  k_noise<<<dim3(4, NB), 256, 0, stream>>>(noise, n_l, frames);

  // oscillator bank
  k_chunksum<<<dim3((NB*NOSC*NCHUNK)/256), 256, 0, stream>>>(f_buf, cbase);
  k_scan<<<dim3(32), 64, 0, stream>>>(cbase);
  k_osc<<<dim3(NCHUNK, NB), 128, 0, stream>>>(f_buf, l_buf, cbase, frames, sig);

  // normalize + crop
  k_max<<<dim3(NB), 256, 0, stream>>>(sig, maxa);
  k_final<<<dim3(NTOT/256, NB), 256, 0, stream>>>(sig, maxa, out);
}

// Round 4
// 1898.270 us; speedup vs baseline: 2.3760x; 1.5133x over previous
//
#include <hip/hip_runtime.h>
#include <cstdio>
#include <math.h>

#define NB 16
#define NC 512
#define T0 64
#define NOSC 128
#define UPLEN 24576
#define NTOT 16384
#define NWIN 32
#define NFRAMES 1024
#define NCROP 4096
#define NCHUNK 96
#define CHT 256

#define TWO_PI_D 6.283185307179586
#define INV_2PI_D 0.15915494309189535
#define K_PHASE (6.283185307179586/11025.0)

static __device__ __forceinline__ float lrelu_f(float x){ return x > 0.f ? x : 0.2f*x; }

// ---------------- tables: centers (np.geomspace(20, 5492.5, 128)) + erbs ----------------
__global__ void k_tables(float* __restrict__ centers, float* __restrict__ erbs){
  int o = threadIdx.x;
  if (o < NOSC){
    double lg0 = log10(20.0);
    double lg1 = log10(5492.5);
    double e = (o == NOSC-1) ? lg1 : (o*(lg1-lg0))/(double)(NOSC-1) + lg0;
    float c = (float)pow(10.0, e);
    centers[o] = c;
    erbs[o] = c*0.108f + 24.7f;
  }
}

// ---------------- pointwise conv + lrelu (f64 accumulate) ----------------
__global__ __launch_bounds__(256) void k_conv1(const float* __restrict__ in, const float* __restrict__ w,
                                               float* __restrict__ out, int Cin, int Cout){
  int b = blockIdx.x;
  int lane = threadIdx.x & 63;
  int wv = __builtin_amdgcn_readfirstlane(threadIdx.x >> 6);
  int co0 = blockIdx.y*16 + wv*4;
  const float* inb = in + (size_t)b*Cin*T0 + lane;
  double a[4] = {0.0,0.0,0.0,0.0};
  for (int ci = 0; ci < Cin; ++ci){
    double v = (double)inb[(size_t)ci*T0];
    #pragma unroll
    for (int j = 0; j < 4; ++j) a[j] += v * (double)w[(size_t)(co0+j)*Cin + ci];
  }
  #pragma unroll
  for (int j = 0; j < 4; ++j)
    out[((size_t)b*Cout + co0 + j)*T0 + lane] = lrelu_f((float)a[j]);
}

// ---------------- k=3 conv + lrelu (pad 1, f64 accumulate, shfl neighbors) ----------------
__global__ __launch_bounds__(256) void k_conv3(const float* __restrict__ in, const float* __restrict__ w,
                                               float* __restrict__ out){
  int b = blockIdx.x;
  int lane = threadIdx.x & 63;
  int wv = __builtin_amdgcn_readfirstlane(threadIdx.x >> 6);
  int co0 = blockIdx.y*16 + wv*4;
  const float* inb = in + (size_t)b*NC*T0;
  double a0[4] = {0.0,0.0,0.0,0.0};
  double a1[4] = {0.0,0.0,0.0,0.0};
  for (int ci = 0; ci < NC; ci += 2){
    float v0 = inb[(size_t)ci*T0 + lane];
    float v1 = inb[(size_t)(ci+1)*T0 + lane];
    float v0m = __shfl_up(v0, 1);  float v1m = __shfl_up(v1, 1);
    float v0p = __shfl_down(v0, 1);float v1p = __shfl_down(v1, 1);
    if (lane == 0){ v0m = 0.f; v1m = 0.f; }
    if (lane == 63){ v0p = 0.f; v1p = 0.f; }
    #pragma unroll
    for (int j = 0; j < 4; ++j){
      const float* wp0 = w + ((size_t)(co0+j)*NC + ci)*3;
      a0[j] += (double)wp0[0]*(double)v0m + (double)wp0[1]*(double)v0 + (double)wp0[2]*(double)v0p;
      a1[j] += (double)wp0[3]*(double)v1m + (double)wp0[4]*(double)v1 + (double)wp0[5]*(double)v1p;
    }
  }
  #pragma unroll
  for (int j = 0; j < 4; ++j)
    out[((size_t)b*NC + co0 + j)*T0 + lane] = lrelu_f((float)(a0[j] + a1[j]));
}

// ---------------- freq head ----------------
__global__ __launch_bounds__(256) void k_freq(const float* __restrict__ h, const float* __restrict__ w,
                                              const float* __restrict__ centers, const float* __restrict__ erbs,
                                              float* __restrict__ l_buf, float* __restrict__ f_buf){
  int b = blockIdx.x;
  int lane = threadIdx.x & 63;
  int wv = __builtin_amdgcn_readfirstlane(threadIdx.x >> 6);
  int o0 = blockIdx.y*16 + wv*4;           // 0..255
  const float* hb = h + (size_t)b*NC*T0 + lane;
  double a[4] = {0.0,0.0,0.0,0.0};
  for (int ci = 0; ci < NC; ++ci){
    double v = (double)hb[(size_t)ci*T0];
    #pragma unroll
    for (int j = 0; j < 4; ++j) a[j] += v * (double)w[(size_t)(o0+j)*NC + ci];
  }
  #pragma unroll
  for (int j = 0; j < 4; ++j){
    int o = o0 + j;
    if (o < NOSC){
      l_buf[((size_t)b*NOSC + o)*T0 + lane] = (float)(a[j]*a[j]);
    } else {
      int oo = o - NOSC;
      double fv = (double)centers[oo] + tanh(a[j])*0.5*(double)erbs[oo];
      f_buf[((size_t)b*NOSC + oo)*T0 + lane] = (float)fv;
    }
  }
}

// ---------------- weight prep: collapse k7 upsample-conv into even/odd 4-tap pairs ----------------
__global__ __launch_bounds__(256) void k_prepw(const float* __restrict__ w, float* __restrict__ w8){
  int idx = blockIdx.x*256 + threadIdx.x;     // co*512+ci
  if (idx >= NC*NC) return;
  const float* wp = w + (size_t)idx*7;
  float w0 = wp[0], w1 = wp[1], w2 = wp[2], w3 = wp[3], w4 = wp[4], w5 = wp[5], w6 = wp[6];
  float* o = w8 + (size_t)idx*8;
  o[0] = w0;      o[1] = w1+w2;  o[2] = w3+w4;  o[3] = w5+w6;
  o[4] = w0+w1;   o[5] = w2+w3;  o[6] = w4+w5;  o[7] = w6;
}

// ---------------- fused nearest-x2-upsample + k7 conv + bias + lrelu ----------------
// LDS-staged input, SGPR (s_load) weights, async-STAGE split (issue-early / write-late).
// wave -> 4 co (wave-uniform via readfirstlane); lane -> TSL input samples (2*TSL outputs).
template<int TSL>
__global__ __launch_bounds__(256) void k_nlconv3(const float* __restrict__ in, const float* __restrict__ w8,
                                                 const float* __restrict__ bias, float* __restrict__ out, int Tin){
  constexpr int TS = 64*TSL;
  constexpr int RS = TS + 8;
  constexpr int CC = 32;
  constexpr int NLD = CC*(RS/4);                 // float4 stage elements per chunk
  constexpr int NV = (NLD + 255)/256;            // per-thread stage registers
  __shared__ float lds[CC*RS];
  const int b = blockIdx.z;
  const int lane = threadIdx.x & 63;
  const int wv = __builtin_amdgcn_readfirstlane(threadIdx.x >> 6);
  const int co0 = blockIdx.x*16 + wv*4;
  const int TS0 = blockIdx.y*TS;
  const int tid = threadIdx.x;
  float acc[4][2*TSL];
  #pragma unroll
  for (int j4 = 0; j4 < 4; ++j4)
    #pragma unroll
    for (int j = 0; j < 2*TSL; ++j) acc[j4][j] = 0.f;
  const float* inb = in + (size_t)b*NC*Tin;

  float4 stg[NV];
  auto load_chunk = [&](int cc0){
    #pragma unroll
    for (int u = 0; u < NV; ++u){
      int v = tid + u*256;
      if (v < NLD){
        int cl = v / (RS/4);
        int p = TS0 - 4 + (v - cl*(RS/4))*4;     // 4-aligned; fully in or fully out of [0,Tin)
        float4 val = make_float4(0.f, 0.f, 0.f, 0.f);
        if (p >= 0 && p < Tin) val = *(const float4*)(inb + (size_t)(cc0+cl)*Tin + p);
        stg[u] = val;
      }
    }
  };

  load_chunk(0);
  for (int cc0 = 0; cc0 < NC; cc0 += CC){
    __syncthreads();                             // previous chunk's compute done
    #pragma unroll
    for (int u = 0; u < NV; ++u){
      int v = tid + u*256;
      if (v < NLD){
        int cl = v / (RS/4);
        int rv = (v - cl*(RS/4))*4;
        *(float4*)(lds + cl*RS + rv) = stg[u];
      }
    }
    __syncthreads();                             // LDS ready
    if (cc0 + CC < NC) load_chunk(cc0 + CC);     // prefetch next chunk; latency hides under compute

    #pragma unroll 4
    for (int cl = 0; cl < CC; ++cl){
      int ci = cc0 + cl;
      float rr[TSL+4];
      if constexpr (TSL == 2){
        const float2* lp2 = (const float2*)(lds + cl*RS + lane*2 + 2);
        float2 q0 = lp2[0], q1 = lp2[1], q2 = lp2[2];
        rr[0] = q0.x; rr[1] = q0.y; rr[2] = q1.x; rr[3] = q1.y; rr[4] = q2.x; rr[5] = q2.y;
      } else {
        const float* lp = lds + cl*RS + lane + 2;
        #pragma unroll
        for (int m = 0; m < TSL+4; ++m) rr[m] = lp[m];
      }
      #pragma unroll
      for (int j4 = 0; j4 < 4; ++j4){
        // co0 is SGPR-uniform -> these compile to s_load through the constant cache
        const float4* wp = (const float4*)(w8 + ((size_t)(co0+j4)*NC + ci)*8);
        float4 we = wp[0], wo = wp[1];
        #pragma unroll
        for (int jj = 0; jj < TSL; ++jj){
          acc[j4][2*jj]   += we.x*rr[jj]   + we.y*rr[jj+1] + we.z*rr[jj+2] + we.w*rr[jj+3];
          acc[j4][2*jj+1] += wo.x*rr[jj+1] + wo.y*rr[jj+2] + wo.z*rr[jj+3] + wo.w*rr[jj+4];
        }
      }
    }
  }
  const int Tout = 2*Tin;
  #pragma unroll
  for (int j4 = 0; j4 < 4; ++j4){
    float bv = bias[co0+j4];
    float* ob = out + ((size_t)b*NC + co0 + j4)*Tout + 2*TS0 + lane*(2*TSL);
    #pragma unroll
    for (int j = 0; j < 2*TSL; ++j) ob[j] = lrelu_f(acc[j4][j] + bv);
  }
}

// ---------------- noise-loudness output ----------------
__global__ __launch_bounds__(256) void k_nlout(const float* __restrict__ y3, const float* __restrict__ w,
                                               float* __restrict__ n_l){
  int b = blockIdx.y;
  int j = blockIdx.x*256 + threadIdx.x;   // 0..1023
  float acc[17];
  #pragma unroll
  for (int k = 0; k < 17; ++k) acc[k] = 0.f;
  const float* yb = y3 + (size_t)b*NC*NFRAMES + j;
  for (int ci = 0; ci < NC; ++ci){
    float v = yb[(size_t)ci*NFRAMES];
    #pragma unroll
    for (int k = 0; k < 17; ++k) acc[k] += v * w[k*NC + ci];
  }
  #pragma unroll
  for (int k = 0; k < 17; ++k)
    n_l[((size_t)b*17 + k)*NFRAMES + j] = acc[k]*acc[k];
}

// ---------------- noise bank: per-frame DFT-filter ----------------
__global__ __launch_bounds__(256) void k_noise(const float* __restrict__ noise, const float* __restrict__ n_l,
                                               float* __restrict__ frames){
  __shared__ float ctab[NWIN], stab[NWIN];
  int tid = threadIdx.x;
  if (tid < NWIN){
    double ang = (TWO_PI_D/NWIN)*tid;
    ctab[tid] = (float)cos(ang);
    stab[tid] = (float)sin(ang);
  }
  __syncthreads();
  int j = blockIdx.x*256 + tid;
  int b = blockIdx.y;
  const float* src = noise + ((size_t)b*NFRAMES + j)*NWIN;
  float nz[NWIN];
  #pragma unroll
  for (int n = 0; n < NWIN; ++n) nz[n] = src[n]*2.f - 1.f;
  float y[NWIN];
  #pragma unroll
  for (int n = 0; n < NWIN; ++n) y[n] = 0.f;
  const float* g = n_l + (size_t)b*17*NFRAMES + j;
  for (int k = 0; k < 17; ++k){
    float A = 0.f, Bv = 0.f;
    int m = 0;
    #pragma unroll
    for (int n = 0; n < NWIN; ++n){
      A  += nz[n]*ctab[m];
      Bv += nz[n]*stab[m];
      m = (m + k) & (NWIN-1);
    }
    float gk = g[(size_t)k*NFRAMES];
    float sc = (k == 0 || k == 16) ? 1.f : 2.f;
    float ga = sc*gk*A, gb = sc*gk*Bv;
    m = 0;
    #pragma unroll
    for (int n = 0; n < NWIN; ++n){
      y[n] += ga*ctab[m] + gb*stab[m];
      m = (m + k) & (NWIN-1);
    }
  }
  float* dst = frames + ((size_t)b*NFRAMES + j)*NWIN;
  #pragma unroll
  for (int n = 0; n < NWIN; ++n) dst[n] = y[n] * (1.f/NWIN);
}

// ---------------- oscillator phase: per-chunk sums (f64) ----------------
__global__ __launch_bounds__(256) void k_chunksum(const float* __restrict__ f_buf, double* __restrict__ cb){
  int idx = blockIdx.x*256 + threadIdx.x;      // NB*NOSC*NCHUNK
  int bo = idx & (NB*NOSC - 1);
  int c  = idx >> 11;
  const float* f = f_buf + (size_t)bo*T0;
  double s = 0.0;
  int t0 = c*CHT;
  int cached = -1000; float f0 = 0.f, f1 = 0.f;
  for (int i = 0; i < CHT; ++i){
    int t = t0 + i;
    double coord = (t + 0.5)*(1.0/384.0) - 0.5;
    double fl = floor(coord);
    int lo = (int)fl;
    float wfr = (float)(coord - fl);
    if (lo != cached){
      cached = lo;
      int i0 = lo < 0 ? 0 : (lo > 63 ? 63 : lo);
      int i1 = lo+1 < 0 ? 0 : (lo+1 > 63 ? 63 : lo+1);
      f0 = f[i0]; f1 = f[i1];
    }
    float v = f0*(1.f - wfr) + f1*wfr;
    v = fminf(fmaxf(v, 20.f), 5512.5f);
    s += (double)v;
  }
  cb[(size_t)bo*NCHUNK + c] = s;
}

__global__ void k_scan(double* __restrict__ cb){
  int bo = blockIdx.x*64 + threadIdx.x;
  if (bo < NB*NOSC){
    double* p = cb + (size_t)bo*NCHUNK;
    double run = 0.0;
    for (int c = 0; c < NCHUNK; ++c){ double v = p[c]; p[c] = run; run += v; }
  }
}

// ---------------- oscillator bank + noise add ----------------
__global__ __launch_bounds__(128) void k_osc(const float* __restrict__ f_buf, const float* __restrict__ l_buf,
                                             const double* __restrict__ cb, const float* __restrict__ frames,
                                             float* __restrict__ sig){
  int c = blockIdx.x;
  int b = blockIdx.y;
  int o = threadIdx.x;
  __shared__ float tile[64*129];
  __shared__ float harm[256];
  __shared__ float red[128];
  const float* f = f_buf + ((size_t)b*NOSC + o)*T0;
  const float* l = l_buf + ((size_t)b*NOSC + o)*T0;
  double sum = cb[((size_t)b*NOSC + o)*NCHUNK + c];
  int tstart = c*CHT;
  int cached = -1000; float f0 = 0.f, f1 = 0.f, l0 = 0.f, l1 = 0.f;
  for (int sub = 0; sub < 4; ++sub){
    for (int i = 0; i < 64; ++i){
      int t = tstart + sub*64 + i;
      double coord = (t + 0.5)*(1.0/384.0) - 0.5;
      double fl = floor(coord);
      int lo = (int)fl;
      float wfr = (float)(coord - fl);
      if (lo != cached){
        cached = lo;
        int i0 = lo < 0 ? 0 : (lo > 63 ? 63 : lo);
        int i1 = lo+1 < 0 ? 0 : (lo+1 > 63 ? 63 : lo+1);
        f0 = f[i0]; f1 = f[i1]; l0 = l[i0]; l1 = l[i1];
      }
      float fv = f0*(1.f - wfr) + f1*wfr;
      fv = fminf(fmaxf(fv, 20.f), 5512.5f);
      float lv = l0*(1.f - wfr) + l1*wfr;
      sum += (double)fv;
      double ph = sum * K_PHASE;
      double q = floor(ph * INV_2PI_D);
      float phw = (float)(ph - q*TWO_PI_D);
      tile[i*129 + o] = sinf(phw) * lv;
    }
    __syncthreads();
    {
      int row = o & 63, half = o >> 6;
      float s = 0.f;
      const float* tp = tile + row*129 + half*64;
      for (int j = 0; j < 64; ++j) s += tp[j];
      red[row*2 + half] = s;
    }
    __syncthreads();
    if (o < 64) harm[sub*64 + o] = red[o*2] + red[o*2 + 1];
    __syncthreads();
  }
  for (int i = o; i < CHT; i += 128){
    int t = tstart + i;
    float v = harm[i];
    int tn = t - NCROP;
    if (tn >= 0 && tn < NTOT){
      int j1 = tn >> 4, n1 = tn & 15;
      float nv = frames[((size_t)b*NFRAMES + j1)*NWIN + n1];
      if (j1 > 0) nv += frames[((size_t)b*NFRAMES + j1 - 1)*NWIN + n1 + 16];
      v += nv;
    }
    sig[(size_t)b*UPLEN + t] = v;
  }
}

// ---------------- per-batch max |sig| ----------------
__global__ __launch_bounds__(256) void k_max(const float* __restrict__ sig, float* __restrict__ maxa){
  int b = blockIdx.x;
  float m = 0.f;
  for (int i = threadIdx.x; i < UPLEN; i += 256)
    m = fmaxf(m, fabsf(sig[(size_t)b*UPLEN + i]));
  #pragma unroll
  for (int off = 32; off > 0; off >>= 1)
    m = fmaxf(m, __shfl_xor(m, off, 64));
  __shared__ float sm[4];
  if ((threadIdx.x & 63) == 0) sm[threadIdx.x >> 6] = m;
  __syncthreads();
  if (threadIdx.x == 0)
    maxa[b] = fmaxf(fmaxf(sm[0], sm[1]), fmaxf(sm[2], sm[3]));
}

// ---------------- normalize + crop ----------------
__global__ __launch_bounds__(256) void k_final(const float* __restrict__ sig, const float* __restrict__ maxa,
                                               float* __restrict__ out){
  int b = blockIdx.y;
  int i = blockIdx.x*256 + threadIdx.x;
  out[(size_t)b*NTOT + i] = sig[(size_t)b*UPLEN + NCROP + i] / (maxa[b] + 1e-8f);
}

extern "C" void kernel_launch(void* const* d_in, const int* in_sizes, int n_in,
                              void* d_out, int out_size, void* d_ws, size_t ws_size,
                              hipStream_t stream)
{
  (void)in_sizes; (void)n_in;
  const float* x     = (const float*)d_in[0];
  const float* w0    = (const float*)d_in[1];
  const float* w1    = (const float*)d_in[2];
  const float* w2    = (const float*)d_in[3];
  const float* w3    = (const float*)d_in[4];
  const float* wf    = (const float*)d_in[5];
  const float* wnl[4] = {(const float*)d_in[6], (const float*)d_in[8], (const float*)d_in[10], (const float*)d_in[12]};
  const float* bnl[4] = {(const float*)d_in[7], (const float*)d_in[9], (const float*)d_in[11], (const float*)d_in[13]};
  const float* wno   = (const float*)d_in[14];
  const float* noise = (const float*)d_in[15];
  float* out = (float*)d_out;

  char* base = (char*)d_ws;
  size_t off = 0;
  auto carve = [&](size_t bytes) -> void* {
    void* r = base + off;
    off += (bytes + 255) & ~(size_t)255;
    return r;
  };
  double* cbase  = (double*)carve(sizeof(double)*(size_t)NB*NOSC*NCHUNK);
  float* h_a     = (float*)carve(4ull*NB*NC*T0);
  float* h_b     = (float*)carve(4ull*NB*NC*T0);
  float* l_buf   = (float*)carve(4ull*NB*NOSC*T0);
  float* f_buf   = (float*)carve(4ull*NB*NOSC*T0);
  float* Vbuf    = (float*)carve(4ull*NB*NC*512);    // y0 then y2
  float* Ubuf    = (float*)carve(4ull*NB*NC*1024);   // y1 then y3
  float* n_l     = (float*)carve(4ull*NB*17*NFRAMES);
  float* frames  = (float*)carve(4ull*NB*NFRAMES*NWIN);
  float* sig     = (float*)carve(4ull*NB*UPLEN);
  float* maxa    = (float*)carve(4ull*NB);
  float* centers = (float*)carve(4ull*NOSC);
  float* erbs    = (float*)carve(4ull*NOSC);
  float* w8buf   = (float*)carve(4ull*NC*NC*8);      // collapsed weights, reused per layer
  if (off > ws_size){
    fprintf(stderr, "kernel_launch: workspace too small: need %zu bytes, have %zu\n", off, ws_size);
    return;
  }
  if (out_size != NB*NTOT){
    fprintf(stderr, "kernel_launch: unexpected out_size %d (want %d)\n", out_size, NB*NTOT);
  }

  k_tables<<<1, 128, 0, stream>>>(centers, erbs);

  // main conv stack
  k_conv1<<<dim3(NB, 32), 256, 0, stream>>>(x, w0, h_a, 256, 512);
  k_conv3<<<dim3(NB, 32), 256, 0, stream>>>(h_a, w1, h_b);
  k_conv3<<<dim3(NB, 32), 256, 0, stream>>>(h_b, w2, h_a);
  k_conv3<<<dim3(NB, 32), 256, 0, stream>>>(h_a, w3, h_b);   // h = h_b

  // freq / loudness head
  k_freq<<<dim3(NB, 16), 256, 0, stream>>>(h_b, wf, centers, erbs, l_buf, f_buf);

  // noise-loudness branch (LDS-staged fused upsample-x2 + conv7 + bias + lrelu)
  const int PREP_BLKS = (NC*NC + 255)/256;
  k_prepw<<<dim3(PREP_BLKS), 256, 0, stream>>>(wnl[0], w8buf);
  k_nlconv3<1><<<dim3(32, 1, NB), 256, 0, stream>>>(h_b,  w8buf, bnl[0], Vbuf, 64);
  k_prepw<<<dim3(PREP_BLKS), 256, 0, stream>>>(wnl[1], w8buf);
  k_nlconv3<2><<<dim3(32, 1, NB), 256, 0, stream>>>(Vbuf, w8buf, bnl[1], Ubuf, 128);
  k_prepw<<<dim3(PREP_BLKS), 256, 0, stream>>>(wnl[2], w8buf);
  k_nlconv3<2><<<dim3(32, 2, NB), 256, 0, stream>>>(Ubuf, w8buf, bnl[2], Vbuf, 256);
  k_prepw<<<dim3(PREP_BLKS), 256, 0, stream>>>(wnl[3], w8buf);
  k_nlconv3<2><<<dim3(32, 4, NB), 256, 0, stream>>>(Vbuf, w8buf, bnl[3], Ubuf, 512);
  k_nlout<<<dim3(4, NB), 256, 0, stream>>>(Ubuf, wno, n_l);

  // noise bank
  k_noise<<<dim3(4, NB), 256, 0, stream>>>(noise, n_l, frames);

  // oscillator bank
  k_chunksum<<<dim3((NB*NOSC*NCHUNK)/256), 256, 0, stream>>>(f_buf, cbase);
  k_scan<<<dim3(32), 64, 0, stream>>>(cbase);
  k_osc<<<dim3(NCHUNK, NB), 128, 0, stream>>>(f_buf, l_buf, cbase, frames, sig);

  // normalize + crop
  k_max<<<dim3(NB), 256, 0, stream>>>(sig, maxa);
  k_final<<<dim3(NTOT/256, NB), 256, 0, stream>>>(sig, maxa, out);
}

// Round 5
// 1732.078 us; speedup vs baseline: 2.6040x; 1.0959x over previous
//
#include <hip/hip_runtime.h>
#include <cstdio>
#include <math.h>

#define NB 16
#define NC 512
#define T0 64
#define NOSC 128
#define UPLEN 24576
#define NTOT 16384
#define NWIN 32
#define NFRAMES 1024
#define NCROP 4096
#define NCHUNK 96
#define CHT 256

#define TWO_PI_D 6.283185307179586
#define INV_2PI_D 0.15915494309189535
#define K_PHASE (6.283185307179586/11025.0)

typedef unsigned short u16;
typedef short bf16x8 __attribute__((ext_vector_type(8)));
typedef short short8 __attribute__((ext_vector_type(8)));
typedef float f32x4 __attribute__((ext_vector_type(4)));

static __device__ __forceinline__ float lrelu_f(float x){ return x > 0.f ? x : 0.2f*x; }

static __device__ __forceinline__ u16 bf16_rne(float x){
  unsigned u = __float_as_uint(x);
  unsigned r = (u + 0x7FFFu + ((u >> 16) & 1u)) >> 16;
  return (u16)r;
}
static __device__ __forceinline__ void bf16_split(float x, u16& h, u16& l){
  h = bf16_rne(x);
  float hf = __uint_as_float(((unsigned)h) << 16);
  l = bf16_rne(x - hf);
}

// ---------------- tables ----------------
__global__ void k_tables(float* __restrict__ centers, float* __restrict__ erbs){
  int o = threadIdx.x;
  if (o < NOSC){
    double lg0 = log10(20.0);
    double lg1 = log10(5492.5);
    double e = (o == NOSC-1) ? lg1 : (o*(lg1-lg0))/(double)(NOSC-1) + lg0;
    float c = (float)pow(10.0, e);
    centers[o] = c;
    erbs[o] = c*0.108f + 24.7f;
  }
}

// ---------------- pointwise conv + lrelu (f64 accumulate) ----------------
__global__ __launch_bounds__(256) void k_conv1(const float* __restrict__ in, const float* __restrict__ w,
                                               float* __restrict__ out, int Cin, int Cout){
  int b = blockIdx.x;
  int lane = threadIdx.x & 63;
  int wv = __builtin_amdgcn_readfirstlane(threadIdx.x >> 6);
  int co0 = blockIdx.y*16 + wv*4;
  const float* inb = in + (size_t)b*Cin*T0 + lane;
  double a[4] = {0.0,0.0,0.0,0.0};
  for (int ci = 0; ci < Cin; ++ci){
    double v = (double)inb[(size_t)ci*T0];
    #pragma unroll
    for (int j = 0; j < 4; ++j) a[j] += v * (double)w[(size_t)(co0+j)*Cin + ci];
  }
  #pragma unroll
  for (int j = 0; j < 4; ++j)
    out[((size_t)b*Cout + co0 + j)*T0 + lane] = lrelu_f((float)a[j]);
}

// ---------------- k=3 conv + lrelu ----------------
__global__ __launch_bounds__(256) void k_conv3(const float* __restrict__ in, const float* __restrict__ w,
                                               float* __restrict__ out){
  int b = blockIdx.x;
  int lane = threadIdx.x & 63;
  int wv = __builtin_amdgcn_readfirstlane(threadIdx.x >> 6);
  int co0 = blockIdx.y*16 + wv*4;
  const float* inb = in + (size_t)b*NC*T0;
  double a0[4] = {0.0,0.0,0.0,0.0};
  double a1[4] = {0.0,0.0,0.0,0.0};
  for (int ci = 0; ci < NC; ci += 2){
    float v0 = inb[(size_t)ci*T0 + lane];
    float v1 = inb[(size_t)(ci+1)*T0 + lane];
    float v0m = __shfl_up(v0, 1);  float v1m = __shfl_up(v1, 1);
    float v0p = __shfl_down(v0, 1);float v1p = __shfl_down(v1, 1);
    if (lane == 0){ v0m = 0.f; v1m = 0.f; }
    if (lane == 63){ v0p = 0.f; v1p = 0.f; }
    #pragma unroll
    for (int j = 0; j < 4; ++j){
      const float* wp0 = w + ((size_t)(co0+j)*NC + ci)*3;
      a0[j] += (double)wp0[0]*(double)v0m + (double)wp0[1]*(double)v0 + (double)wp0[2]*(double)v0p;
      a1[j] += (double)wp0[3]*(double)v1m + (double)wp0[4]*(double)v1 + (double)wp0[5]*(double)v1p;
    }
  }
  #pragma unroll
  for (int j = 0; j < 4; ++j)
    out[((size_t)b*NC + co0 + j)*T0 + lane] = lrelu_f((float)(a0[j] + a1[j]));
}

// ---------------- freq head ----------------
__global__ __launch_bounds__(256) void k_freq(const float* __restrict__ h, const float* __restrict__ w,
                                              const float* __restrict__ centers, const float* __restrict__ erbs,
                                              float* __restrict__ l_buf, float* __restrict__ f_buf){
  int b = blockIdx.x;
  int lane = threadIdx.x & 63;
  int wv = __builtin_amdgcn_readfirstlane(threadIdx.x >> 6);
  int o0 = blockIdx.y*16 + wv*4;
  const float* hb = h + (size_t)b*NC*T0 + lane;
  double a[4] = {0.0,0.0,0.0,0.0};
  for (int ci = 0; ci < NC; ++ci){
    double v = (double)hb[(size_t)ci*T0];
    #pragma unroll
    for (int j = 0; j < 4; ++j) a[j] += v * (double)w[(size_t)(o0+j)*NC + ci];
  }
  #pragma unroll
  for (int j = 0; j < 4; ++j){
    int o = o0 + j;
    if (o < NOSC){
      l_buf[((size_t)b*NOSC + o)*T0 + lane] = (float)(a[j]*a[j]);
    } else {
      int oo = o - NOSC;
      double fv = (double)centers[oo] + tanh(a[j])*0.5*(double)erbs[oo];
      f_buf[((size_t)b*NOSC + oo)*T0 + lane] = (float)fv;
    }
  }
}

// ---------------- weight prep: collapse k7 -> 8 taps (4 even, 4 odd), split bf16 hi/lo ----------------
// layout: W[tap][co][ci], tap 0..3 = even (shift s=m-2), 4..7 = odd (shift s=m-1)
__global__ __launch_bounds__(256) void k_prepw2(const float* __restrict__ w, u16* __restrict__ Wh, u16* __restrict__ Wl){
  int co = blockIdx.x;
  int ci = blockIdx.y*256 + threadIdx.x;
  const float* wp = w + ((size_t)co*NC + ci)*7;
  float w0=wp[0],w1=wp[1],w2=wp[2],w3=wp[3],w4=wp[4],w5=wp[5],w6=wp[6];
  float tv[8] = {w0, w1+w2, w3+w4, w5+w6,  w0+w1, w2+w3, w4+w5, w6};
  #pragma unroll
  for (int m = 0; m < 8; ++m){
    u16 h, l; bf16_split(tv[m], h, l);
    size_t o = ((size_t)m*NC + co)*NC + ci;
    Wh[o] = h; Wl[o] = l;
  }
}

// ---------------- zero the +-2 pad rows of the B (im2col) buffers ----------------
__global__ void k_zpad(u16* __restrict__ Bh, u16* __restrict__ Bl, int Tin){
  int b = blockIdx.x;
  for (int i = threadIdx.x; i < 4*NC; i += 256){
    int row = i >> 9;                       // 0..3
    int arow = (row < 2) ? row : Tin + row; // rows 0,1,Tin+2,Tin+3
    size_t o = ((size_t)b*(Tin+4) + arow)*NC + (i & (NC-1));
    Bh[o] = 0;
    if (Bl) Bl[o] = 0;
  }
}

// ---------------- activation prep: fp32 [ci][t] -> bf16 hi/lo [t][ci] (row offset +2) ----------------
__global__ __launch_bounds__(256) void k_prepb(const float* __restrict__ in, u16* __restrict__ Bh,
                                               u16* __restrict__ Bl, int Tin){
  __shared__ float lds[64][65];
  int b = blockIdx.z, ci0 = blockIdx.x*64, t0 = blockIdx.y*64;
  int tid = threadIdx.x;
  #pragma unroll
  for (int u = 0; u < 4; ++u){
    int v = tid + u*256;
    int ci = v >> 4, tc = (v & 15)*4;
    float4 x = *(const float4*)(in + ((size_t)b*NC + ci0 + ci)*Tin + t0 + tc);
    lds[ci][tc+0] = x.x; lds[ci][tc+1] = x.y; lds[ci][tc+2] = x.z; lds[ci][tc+3] = x.w;
  }
  __syncthreads();
  int r = tid >> 2, g = tid & 3;
  short8 h0, h1, l0, l1;
  #pragma unroll
  for (int jj = 0; jj < 8; ++jj){
    u16 hh, ll;
    bf16_split(lds[g*16+jj][r], hh, ll);      h0[jj] = (short)hh; l0[jj] = (short)ll;
    bf16_split(lds[g*16+8+jj][r], hh, ll);    h1[jj] = (short)hh; l1[jj] = (short)ll;
  }
  size_t obase = ((size_t)b*(Tin+4) + 2 + t0 + r)*NC + ci0 + g*16;
  *(short8*)(Bh + obase) = h0;
  *(short8*)(Bh + obase + 8) = h1;
  if (Bl){ *(short8*)(Bl + obase) = l0; *(short8*)(Bl + obase + 8) = l1; }
}

// ---------------- MFMA upsample-conv: out[b][co][2t+p] = lrelu(bias + sum W.in) ----------------
// block = 4 waves (2co x 2t); wave tile 64co x 32t, both parities.
// A frag: lane holds W[tap][co_w + c*16 + (l&15)][ci0 + (l>>4)*8 + j]
// B frag: lane holds B[t_w + f*16 + (l&15) + s][ci0 + (l>>4)*8 + j]   (B layout [t][ci])
// split-bf16: C = Ah.Bh + Ah.Bl + Al.Bh  (error ~2^-16)
template<bool USEBL>
__global__ __launch_bounds__(256) void k_nlmfma(const u16* __restrict__ Wh, const u16* __restrict__ Wl,
                                                const u16* __restrict__ Bh, const u16* __restrict__ Bl,
                                                const float* __restrict__ bias, float* __restrict__ out, int Tin){
  const int lane = threadIdx.x & 63;
  const int wv = __builtin_amdgcn_readfirstlane(threadIdx.x >> 6);
  const int r16 = lane & 15, kg = lane >> 4;
  const int co_w = blockIdx.x*128 + (wv >> 1)*64;
  const int t_w  = blockIdx.y*64 + (wv & 1)*32;
  const int b = blockIdx.z;
  const size_t NC2 = (size_t)NC*NC;

  f32x4 acc[2][4][2];
  f32x4 zz = {0.f, 0.f, 0.f, 0.f};
  #pragma unroll
  for (int p = 0; p < 2; ++p)
    #pragma unroll
    for (int c = 0; c < 4; ++c)
      #pragma unroll
      for (int f = 0; f < 2; ++f) acc[p][c][f] = zz;

  // row index into padded B: pad(+2) + (t + s - 2) = t + s, s in [0,4]
  const size_t bRow  = ((size_t)b*(Tin+4) + t_w + r16)*NC + kg*8;
  const size_t aBase = ((size_t)(co_w + r16))*NC + kg*8;

  for (int ci0 = 0; ci0 < NC; ci0 += 32){
    #pragma unroll
    for (int s = 0; s < 5; ++s){
      bf16x8 bh0 = *(const bf16x8*)(Bh + bRow + (size_t)s*NC + ci0);
      bf16x8 bh1 = *(const bf16x8*)(Bh + bRow + (size_t)(s+16)*NC + ci0);
      bf16x8 bl0{}, bl1{};
      if (USEBL){
        bl0 = *(const bf16x8*)(Bl + bRow + (size_t)s*NC + ci0);
        bl1 = *(const bf16x8*)(Bl + bRow + (size_t)(s+16)*NC + ci0);
      }
      #pragma unroll
      for (int e = 0; e < 2; ++e){
        if ((e == 0 && s < 4) || (e == 1 && s >= 1)){
          const int tap = (e == 0) ? s : (3 + s);   // odd tap m=s-1 -> index 4+(s-1)
          bf16x8 ah[4], al[4];
          #pragma unroll
          for (int c = 0; c < 4; ++c){
            size_t ao = (size_t)tap*NC2 + (size_t)(c*16)*NC + aBase + ci0;
            ah[c] = *(const bf16x8*)(Wh + ao);
            al[c] = *(const bf16x8*)(Wl + ao);
          }
          #pragma unroll
          for (int c = 0; c < 4; ++c){
            #pragma unroll
            for (int f = 0; f < 2; ++f){
              bf16x8 bhf = f ? bh1 : bh0;
              f32x4 a = acc[e][c][f];
              a = __builtin_amdgcn_mfma_f32_16x16x32_bf16(ah[c], bhf, a, 0, 0, 0);
              if (USEBL){
                bf16x8 blf = f ? bl1 : bl0;
                a = __builtin_amdgcn_mfma_f32_16x16x32_bf16(ah[c], blf, a, 0, 0, 0);
              }
              a = __builtin_amdgcn_mfma_f32_16x16x32_bf16(al[c], bhf, a, 0, 0, 0);
              acc[e][c][f] = a;
            }
          }
        }
      }
    }
  }

  const int Tout = 2*Tin;
  #pragma unroll
  for (int c = 0; c < 4; ++c){
    #pragma unroll
    for (int r = 0; r < 4; ++r){
      int co = co_w + c*16 + kg*4 + r;
      float bv = bias[co];
      #pragma unroll
      for (int f = 0; f < 2; ++f){
        int t = t_w + f*16 + r16;
        float2 v;
        v.x = lrelu_f(acc[0][c][f][r] + bv);
        v.y = lrelu_f(acc[1][c][f][r] + bv);
        *(float2*)(out + ((size_t)b*NC + co)*Tout + 2*t) = v;
      }
    }
  }
}

// ---------------- noise-loudness output ----------------
__global__ __launch_bounds__(256) void k_nlout(const float* __restrict__ y3, const float* __restrict__ w,
                                               float* __restrict__ n_l){
  int b = blockIdx.y;
  int j = blockIdx.x*256 + threadIdx.x;
  float acc[17];
  #pragma unroll
  for (int k = 0; k < 17; ++k) acc[k] = 0.f;
  const float* yb = y3 + (size_t)b*NC*NFRAMES + j;
  for (int ci = 0; ci < NC; ++ci){
    float v = yb[(size_t)ci*NFRAMES];
    #pragma unroll
    for (int k = 0; k < 17; ++k) acc[k] += v * w[k*NC + ci];
  }
  #pragma unroll
  for (int k = 0; k < 17; ++k)
    n_l[((size_t)b*17 + k)*NFRAMES + j] = acc[k]*acc[k];
}

// ---------------- noise bank ----------------
__global__ __launch_bounds__(256) void k_noise(const float* __restrict__ noise, const float* __restrict__ n_l,
                                               float* __restrict__ frames){
  __shared__ float ctab[NWIN], stab[NWIN];
  int tid = threadIdx.x;
  if (tid < NWIN){
    double ang = (TWO_PI_D/NWIN)*tid;
    ctab[tid] = (float)cos(ang);
    stab[tid] = (float)sin(ang);
  }
  __syncthreads();
  int j = blockIdx.x*256 + tid;
  int b = blockIdx.y;
  const float* src = noise + ((size_t)b*NFRAMES + j)*NWIN;
  float nz[NWIN];
  #pragma unroll
  for (int n = 0; n < NWIN; ++n) nz[n] = src[n]*2.f - 1.f;
  float y[NWIN];
  #pragma unroll
  for (int n = 0; n < NWIN; ++n) y[n] = 0.f;
  const float* g = n_l + (size_t)b*17*NFRAMES + j;
  for (int k = 0; k < 17; ++k){
    float A = 0.f, Bv = 0.f;
    int m = 0;
    #pragma unroll
    for (int n = 0; n < NWIN; ++n){
      A  += nz[n]*ctab[m];
      Bv += nz[n]*stab[m];
      m = (m + k) & (NWIN-1);
    }
    float gk = g[(size_t)k*NFRAMES];
    float sc = (k == 0 || k == 16) ? 1.f : 2.f;
    float ga = sc*gk*A, gb = sc*gk*Bv;
    m = 0;
    #pragma unroll
    for (int n = 0; n < NWIN; ++n){
      y[n] += ga*ctab[m] + gb*stab[m];
      m = (m + k) & (NWIN-1);
    }
  }
  float* dst = frames + ((size_t)b*NFRAMES + j)*NWIN;
  #pragma unroll
  for (int n = 0; n < NWIN; ++n) dst[n] = y[n] * (1.f/NWIN);
}

// ---------------- oscillator phase: per-chunk sums ----------------
__global__ __launch_bounds__(256) void k_chunksum(const float* __restrict__ f_buf, double* __restrict__ cb){
  int idx = blockIdx.x*256 + threadIdx.x;
  int bo = idx & (NB*NOSC - 1);
  int c  = idx >> 11;
  const float* f = f_buf + (size_t)bo*T0;
  double s = 0.0;
  int t0 = c*CHT;
  int cached = -1000; float f0 = 0.f, f1 = 0.f;
  for (int i = 0; i < CHT; ++i){
    int t = t0 + i;
    double coord = (t + 0.5)*(1.0/384.0) - 0.5;
    double fl = floor(coord);
    int lo = (int)fl;
    float wfr = (float)(coord - fl);
    if (lo != cached){
      cached = lo;
      int i0 = lo < 0 ? 0 : (lo > 63 ? 63 : lo);
      int i1 = lo+1 < 0 ? 0 : (lo+1 > 63 ? 63 : lo+1);
      f0 = f[i0]; f1 = f[i1];
    }
    float v = f0*(1.f - wfr) + f1*wfr;
    v = fminf(fmaxf(v, 20.f), 5512.5f);
    s += (double)v;
  }
  cb[(size_t)bo*NCHUNK + c] = s;
}

__global__ void k_scan(double* __restrict__ cb){
  int bo = blockIdx.x*64 + threadIdx.x;
  if (bo < NB*NOSC){
    double* p = cb + (size_t)bo*NCHUNK;
    double run = 0.0;
    for (int c = 0; c < NCHUNK; ++c){ double v = p[c]; p[c] = run; run += v; }
  }
}

// ---------------- oscillator bank + noise add ----------------
__global__ __launch_bounds__(128) void k_osc(const float* __restrict__ f_buf, const float* __restrict__ l_buf,
                                             const double* __restrict__ cb, const float* __restrict__ frames,
                                             float* __restrict__ sig){
  int c = blockIdx.x;
  int b = blockIdx.y;
  int o = threadIdx.x;
  __shared__ float tile[64*129];
  __shared__ float harm[256];
  __shared__ float red[128];
  const float* f = f_buf + ((size_t)b*NOSC + o)*T0;
  const float* l = l_buf + ((size_t)b*NOSC + o)*T0;
  double sum = cb[((size_t)b*NOSC + o)*NCHUNK + c];
  int tstart = c*CHT;
  int cached = -1000; float f0 = 0.f, f1 = 0.f, l0 = 0.f, l1 = 0.f;
  for (int sub = 0; sub < 4; ++sub){
    for (int i = 0; i < 64; ++i){
      int t = tstart + sub*64 + i;
      double coord = (t + 0.5)*(1.0/384.0) - 0.5;
      double fl = floor(coord);
      int lo = (int)fl;
      float wfr = (float)(coord - fl);
      if (lo != cached){
        cached = lo;
        int i0 = lo < 0 ? 0 : (lo > 63 ? 63 : lo);
        int i1 = lo+1 < 0 ? 0 : (lo+1 > 63 ? 63 : lo+1);
        f0 = f[i0]; f1 = f[i1]; l0 = l[i0]; l1 = l[i1];
      }
      float fv = f0*(1.f - wfr) + f1*wfr;
      fv = fminf(fmaxf(fv, 20.f), 5512.5f);
      float lv = l0*(1.f - wfr) + l1*wfr;
      sum += (double)fv;
      double ph = sum * K_PHASE;
      double q = floor(ph * INV_2PI_D);
      float phw = (float)(ph - q*TWO_PI_D);
      tile[i*129 + o] = sinf(phw) * lv;
    }
    __syncthreads();
    {
      int row = o & 63, half = o >> 6;
      float s = 0.f;
      const float* tp = tile + row*129 + half*64;
      for (int j = 0; j < 64; ++j) s += tp[j];
      red[row*2 + half] = s;
    }
    __syncthreads();
    if (o < 64) harm[sub*64 + o] = red[o*2] + red[o*2 + 1];
    __syncthreads();
  }
  for (int i = o; i < CHT; i += 128){
    int t = tstart + i;
    float v = harm[i];
    int tn = t - NCROP;
    if (tn >= 0 && tn < NTOT){
      int j1 = tn >> 4, n1 = tn & 15;
      float nv = frames[((size_t)b*NFRAMES + j1)*NWIN + n1];
      if (j1 > 0) nv += frames[((size_t)b*NFRAMES + j1 - 1)*NWIN + n1 + 16];
      v += nv;
    }
    sig[(size_t)b*UPLEN + t] = v;
  }
}

// ---------------- per-batch max |sig| ----------------
__global__ __launch_bounds__(256) void k_max(const float* __restrict__ sig, float* __restrict__ maxa){
  int b = blockIdx.x;
  float m = 0.f;
  for (int i = threadIdx.x; i < UPLEN; i += 256)
    m = fmaxf(m, fabsf(sig[(size_t)b*UPLEN + i]));
  #pragma unroll
  for (int off = 32; off > 0; off >>= 1)
    m = fmaxf(m, __shfl_xor(m, off, 64));
  __shared__ float sm[4];
  if ((threadIdx.x & 63) == 0) sm[threadIdx.x >> 6] = m;
  __syncthreads();
  if (threadIdx.x == 0)
    maxa[b] = fmaxf(fmaxf(sm[0], sm[1]), fmaxf(sm[2], sm[3]));
}

// ---------------- normalize + crop ----------------
__global__ __launch_bounds__(256) void k_final(const float* __restrict__ sig, const float* __restrict__ maxa,
                                               float* __restrict__ out){
  int b = blockIdx.y;
  int i = blockIdx.x*256 + threadIdx.x;
  out[(size_t)b*NTOT + i] = sig[(size_t)b*UPLEN + NCROP + i] / (maxa[b] + 1e-8f);
}

extern "C" void kernel_launch(void* const* d_in, const int* in_sizes, int n_in,
                              void* d_out, int out_size, void* d_ws, size_t ws_size,
                              hipStream_t stream)
{
  (void)in_sizes; (void)n_in;
  const float* x     = (const float*)d_in[0];
  const float* w0    = (const float*)d_in[1];
  const float* w1    = (const float*)d_in[2];
  const float* w2    = (const float*)d_in[3];
  const float* w3    = (const float*)d_in[4];
  const float* wf    = (const float*)d_in[5];
  const float* wnl[4] = {(const float*)d_in[6], (const float*)d_in[8], (const float*)d_in[10], (const float*)d_in[12]};
  const float* bnl[4] = {(const float*)d_in[7], (const float*)d_in[9], (const float*)d_in[11], (const float*)d_in[13]};
  const float* wno   = (const float*)d_in[14];
  const float* noise = (const float*)d_in[15];
  float* out = (float*)d_out;

  char* base = (char*)d_ws;
  size_t off = 0;
  auto carve = [&](size_t bytes) -> void* {
    void* r = base + off;
    off += (bytes + 255) & ~(size_t)255;
    return r;
  };
  double* cbase  = (double*)carve(sizeof(double)*(size_t)NB*NOSC*NCHUNK);
  float* h_a     = (float*)carve(4ull*NB*NC*T0);
  float* h_b     = (float*)carve(4ull*NB*NC*T0);
  float* l_buf   = (float*)carve(4ull*NB*NOSC*T0);
  float* f_buf   = (float*)carve(4ull*NB*NOSC*T0);
  float* Vbuf    = (float*)carve(4ull*NB*NC*512);    // y0 then y2
  float* Ubuf    = (float*)carve(4ull*NB*NC*1024);   // y1 then y3
  float* n_l     = (float*)carve(4ull*NB*17*NFRAMES);
  float* frames  = (float*)carve(4ull*NB*NFRAMES*NWIN);
  float* sig     = (float*)carve(4ull*NB*UPLEN);
  float* maxa    = (float*)carve(4ull*NB);
  float* centers = (float*)carve(4ull*NOSC);
  float* erbs    = (float*)carve(4ull*NOSC);
  u16* Wh        = (u16*)carve(2ull*8*NC*NC);        // 4.2 MB
  u16* Wl        = (u16*)carve(2ull*8*NC*NC);
  u16* Bh        = (u16*)carve(2ull*NB*(512+4)*NC);  // 8.5 MB (max layer Tin=512)
  if (off > ws_size){
    fprintf(stderr, "kernel_launch: workspace too small: need %zu bytes, have %zu\n", off, ws_size);
    return;
  }
  u16* Bl = nullptr;
  size_t blBytes = ((2ull*NB*(512+4)*NC) + 255) & ~(size_t)255;
  if (off + blBytes <= ws_size){
    Bl = (u16*)carve(2ull*NB*(512+4)*NC);
  } else {
    fprintf(stderr, "kernel_launch: B-lo buffer dropped (ws %zu), using single-bf16 activations\n", ws_size);
  }
  if (out_size != NB*NTOT){
    fprintf(stderr, "kernel_launch: unexpected out_size %d (want %d)\n", out_size, NB*NTOT);
  }

  k_tables<<<1, 128, 0, stream>>>(centers, erbs);

  // main conv stack
  k_conv1<<<dim3(NB, 32), 256, 0, stream>>>(x, w0, h_a, 256, 512);
  k_conv3<<<dim3(NB, 32), 256, 0, stream>>>(h_a, w1, h_b);
  k_conv3<<<dim3(NB, 32), 256, 0, stream>>>(h_b, w2, h_a);
  k_conv3<<<dim3(NB, 32), 256, 0, stream>>>(h_a, w3, h_b);   // h = h_b

  // freq / loudness head
  k_freq<<<dim3(NB, 16), 256, 0, stream>>>(h_b, wf, centers, erbs, l_buf, f_buf);

  // noise-loudness branch: split-bf16 MFMA layers
  auto run_layer = [&](const float* w, const float* bias, const float* inb, float* outb, int Tin){
    k_prepw2<<<dim3(NC, 2), 256, 0, stream>>>(w, Wh, Wl);
    k_zpad<<<dim3(NB), 256, 0, stream>>>(Bh, Bl, Tin);
    k_prepb<<<dim3(NC/64, Tin/64, NB), 256, 0, stream>>>(inb, Bh, Bl, Tin);
    if (Bl) k_nlmfma<true ><<<dim3(NC/128, Tin/64, NB), 256, 0, stream>>>(Wh, Wl, Bh, Bl, bias, outb, Tin);
    else    k_nlmfma<false><<<dim3(NC/128, Tin/64, NB), 256, 0, stream>>>(Wh, Wl, Bh, nullptr, bias, outb, Tin);
  };
  run_layer(wnl[0], bnl[0], h_b,  Vbuf, 64);
  run_layer(wnl[1], bnl[1], Vbuf, Ubuf, 128);
  run_layer(wnl[2], bnl[2], Ubuf, Vbuf, 256);
  run_layer(wnl[3], bnl[3], Vbuf, Ubuf, 512);
  k_nlout<<<dim3(4, NB), 256, 0, stream>>>(Ubuf, wno, n_l);

  // noise bank
  k_noise<<<dim3(4, NB), 256, 0, stream>>>(noise, n_l, frames);

  // oscillator bank
  k_chunksum<<<dim3((NB*NOSC*NCHUNK)/256), 256, 0, stream>>>(f_buf, cbase);
  k_scan<<<dim3(32), 64, 0, stream>>>(cbase);
  k_osc<<<dim3(NCHUNK, NB), 128, 0, stream>>>(f_buf, l_buf, cbase, frames, sig);

  // normalize + crop
  k_max<<<dim3(NB), 256, 0, stream>>>(sig, maxa);
  k_final<<<dim3(NTOT/256, NB), 256, 0, stream>>>(sig, maxa, out);
}